// Round 5
// baseline (606.959 us; speedup 1.0000x reference)
//
#include <hip/hip_runtime.h>
#include <hip/hip_cooperative_groups.h>

namespace cg = cooperative_groups;

#define NN 8192     // nodes
#define NB 32       // graphs
#define NG 256      // nodes per graph
#define NE 65536    // edges per graph type
#define DK 512
#define HC 32
#define DB 2048     // body visual dim
#define DF 512      // face visual dim
#define GRID 512

typedef float v2f __attribute__((ext_vector_type(2)));

#if __has_builtin(__builtin_amdgcn_cvt_pk_f32_fp8) && __has_builtin(__builtin_amdgcn_cvt_pk_fp8_f32)
#define HW_FP8 1
#else
#define HW_FP8 0
#endif

// ---- fp8 e4m3fn helpers (manual fallback only if builtins missing) ----
__device__ __forceinline__ float fp8_dec(unsigned u) {
    unsigned e = (u >> 3) & 15u, m = u & 7u, s = u & 0x80u;
    float v = e ? __uint_as_float(((e + 120u) << 23) | (m << 20))
                : (float)m * 0.001953125f;
    return s ? -v : v;
}
__device__ __forceinline__ unsigned fp8_enc(float x) {
    unsigned sb = (__float_as_uint(x) >> 24) & 0x80u;
    float a = fabsf(x);
    if (a >= 448.f) return sb | 0x7Eu;
    if (a < 0.015625f) {
        int c = (int)rintf(a * 512.f);
        if (c > 7) return sb | 0x08u;
        return sb | (unsigned)c;
    }
    int ex; (void)frexpf(a, &ex);
    float p = ldexpf(a, 1 - ex);
    int m = (int)rintf((p - 1.f) * 8.f);
    int e = ex - 1 + 7;
    if (m == 8) { m = 0; e++; }
    if (e >= 16) return sb | 0x7Eu;
    return sb | (unsigned)(e << 3) | (unsigned)m;
}
__device__ __forceinline__ unsigned pack4_fp8(float x, float y, float z, float w) {
#if HW_FP8
    int u = __builtin_amdgcn_cvt_pk_fp8_f32(x, y, 0, false);
    u = __builtin_amdgcn_cvt_pk_fp8_f32(z, w, u, true);
    return (unsigned)u;
#else
    return fp8_enc(x) | (fp8_enc(y) << 8) | (fp8_enc(z) << 16) | (fp8_enc(w) << 24);
#endif
}
__device__ __forceinline__ float fp8dot4(unsigned a, unsigned b) {
#if HW_FP8
    v2f al = __builtin_amdgcn_cvt_pk_f32_fp8((int)a, false);
    v2f ah = __builtin_amdgcn_cvt_pk_f32_fp8((int)a, true);
    v2f bl = __builtin_amdgcn_cvt_pk_f32_fp8((int)b, false);
    v2f bh = __builtin_amdgcn_cvt_pk_f32_fp8((int)b, true);
    return al.x*bl.x + al.y*bl.y + ah.x*bh.x + ah.y*bh.y;
#else
    float s = 0.f;
    #pragma unroll
    for (int j = 0; j < 4; j++)
        s += fp8_dec((a >> (8*j)) & 255u) * fp8_dec((b >> (8*j)) & 255u);
    return s;
#endif
}
__device__ __forceinline__ float fp8dot16(int4 a, int4 b) {
    return fp8dot4((unsigned)a.x, (unsigned)b.x) + fp8dot4((unsigned)a.y, (unsigned)b.y)
         + fp8dot4((unsigned)a.z, (unsigned)b.z) + fp8dot4((unsigned)a.w, (unsigned)b.w);
}

struct Params {
    const float *vb, *vf, *x, *Wq, *Wk, *Wv, *ln_g, *ln_b, *prelu_a;
    const float *mlp_W, *mlp_b, *np_W, *np_b, *body_W, *body_b, *face_W, *face_b;
    const float *pb_W, *pb_b, *pf_W, *pf_b;
    const int *eib, *eif;
    unsigned *vnb, *vnf;
    float *a_ws, *ns, *hlb, *hlf, *w;
    int *counts, *starts, *cursor, *esrc, *edst;
    float *out;
};

// ===================== single cooperative mega-kernel =====================
__global__ __launch_bounds__(256, 2) void mega_kernel(Params p) {
    cg::grid_group g = cg::this_grid();
    __shared__ float red[4];
    __shared__ float2 xs[NG];
    __shared__ float pm[4][4];
    __shared__ float sm4[4];
    __shared__ int part[256];
    __shared__ float t[4][DK];
    __shared__ float hbuf[4][HC];
    const int bid = blockIdx.x, tid = threadIdx.x;
    const int lane = tid & 63, wave = tid >> 6;
    const int nblk = gridDim.x;

    // ===== Phase A: zero counts (ws is poisoned 0xAA) =====
    for (int i = bid * 256 + tid; i < 2*NN; i += nblk * 256) p.counts[i] = 0;
    g.sync();

    // ===== Phase B: norm->fp8 (register-resident) + degree count + attention =====
    {
        const int B_BODY = NN;            // 1 row / block-iter
        const int B_FACE = NN/4;          // 4 rows / block-iter (1 per wave)
        const int B_CNT  = (2*NE)/256;    // 512
        const int B_TOT  = B_BODY + B_FACE + B_CNT + NB;
        for (int it = bid; it < B_TOT; it += nblk) {
            if (it < B_BODY) {
                const int node = it;
                const float4* r4 = (const float4*)(p.vb + (size_t)node * DB);
                float4 a = r4[tid], b = r4[tid + 256];
                float ss = a.x*a.x + a.y*a.y + a.z*a.z + a.w*a.w
                         + b.x*b.x + b.y*b.y + b.z*b.z + b.w*b.w;
                #pragma unroll
                for (int off = 32; off > 0; off >>= 1) ss += __shfl_down(ss, off);
                if (lane == 0) red[wave] = ss;
                __syncthreads();
                const float inv = rsqrtf(red[0]+red[1]+red[2]+red[3] + 1e-8f);
                unsigned* orow = p.vnb + (size_t)node * (DB/4);
                orow[tid]       = pack4_fp8(a.x*inv, a.y*inv, a.z*inv, a.w*inv);
                orow[tid + 256] = pack4_fp8(b.x*inv, b.y*inv, b.z*inv, b.w*inv);
                __syncthreads();   // guard red[] WAR for next iteration
            } else if (it < B_BODY + B_FACE) {
                const int node = (it - B_BODY) * 4 + wave;
                const float4* r4 = (const float4*)(p.vf + (size_t)node * DF);
                float4 a = r4[lane], b = r4[lane + 64];
                float ss = a.x*a.x + a.y*a.y + a.z*a.z + a.w*a.w
                         + b.x*b.x + b.y*b.y + b.z*b.z + b.w*b.w;
                #pragma unroll
                for (int off = 1; off < 64; off <<= 1) ss += __shfl_xor(ss, off);
                const float inv = rsqrtf(ss + 1e-8f);
                unsigned* orow = p.vnf + (size_t)node * (DF/4);
                orow[lane]      = pack4_fp8(a.x*inv, a.y*inv, a.z*inv, a.w*inv);
                orow[lane + 64] = pack4_fp8(b.x*inv, b.y*inv, b.z*inv, b.w*inv);
            } else if (it < B_BODY + B_FACE + B_CNT) {
                const int e = (it - B_BODY - B_FACE) * 256 + tid;
                if (e < NE) atomicAdd(&p.counts[p.eib[NE + e]], 1);
                else        atomicAdd(&p.counts[NN + p.eif[NE + (e - NE)]], 1);
            } else {
                const int gg = it - (B_BODY + B_FACE + B_CNT);
                xs[tid] = ((const float2*)p.x)[gg*NG + tid];
                const int d = tid * 2;
                float q0a = p.Wq[d],    q0b = p.Wq[d+1];
                float q1a = p.Wq[DK+d], q1b = p.Wq[DK+d+1];
                float k0a = p.Wk[d],    k0b = p.Wk[d+1];
                float k1a = p.Wk[DK+d], k1b = p.Wk[DK+d+1];
                float m00 = q0a*k0a + q0b*k0b;
                float m01 = q0a*k1a + q0b*k1b;
                float m10 = q1a*k0a + q1b*k0b;
                float m11 = q1a*k1a + q1b*k1b;
                #pragma unroll
                for (int off = 32; off > 0; off >>= 1) {
                    m00 += __shfl_down(m00,off); m01 += __shfl_down(m01,off);
                    m10 += __shfl_down(m10,off); m11 += __shfl_down(m11,off);
                }
                if (lane == 0) { pm[wave][0]=m00; pm[wave][1]=m01; pm[wave][2]=m10; pm[wave][3]=m11; }
                __syncthreads();
                if (tid < 4) sm4[tid] = pm[0][tid] + pm[1][tid] + pm[2][tid] + pm[3][tid];
                __syncthreads();
                const float scale = 0.04419417382415922f;  // 1/sqrt(512)
                const float2 xi = xs[tid];
                const float u0 = (xi.x*sm4[0] + xi.y*sm4[2]) * scale;
                const float u1 = (xi.x*sm4[1] + xi.y*sm4[3]) * scale;
                float m = -1e30f;
                for (int j = 0; j < NG; j++) m = fmaxf(m, u0*xs[j].x + u1*xs[j].y);
                float S = 0.f, a0 = 0.f, a1 = 0.f;
                for (int j = 0; j < NG; j++) {
                    float2 xj = xs[j];
                    float pr = __expf(u0*xj.x + u1*xj.y - m);
                    S += pr; a0 += pr*xj.x; a1 += pr*xj.y;
                }
                const float invS = 1.f / S;
                ((float2*)p.a_ws)[gg*NG + tid] = make_float2(a0*invS, a1*invS);
                __syncthreads();
            }
        }
    }
    g.sync();

    // ===== Phase C: exclusive scan (2 blocks) =====
    if (bid < 2) {
        const int cbase = bid * NN;
        const int sbase = bid * (NN + 1);
        int loc[32];
        int sum = 0;
        #pragma unroll
        for (int j = 0; j < 32; j++) { loc[j] = p.counts[cbase + tid*32 + j]; sum += loc[j]; }
        part[tid] = sum;
        __syncthreads();
        for (int off = 1; off < 256; off <<= 1) {
            int v = (tid >= off) ? part[tid - off] : 0;
            __syncthreads();
            part[tid] += v;
            __syncthreads();
        }
        int run = (tid == 0) ? 0 : part[tid - 1];
        #pragma unroll
        for (int j = 0; j < 32; j++) {
            p.starts[sbase + tid*32 + j] = run;
            p.cursor[cbase + tid*32 + j] = run;
            run += loc[j];
        }
        if (tid == 255) p.starts[sbase + NN] = run;
    }
    g.sync();

    // ===== Phase D: node pipeline + CSR fill =====
    {
        const int D_NODE = NN/4;          // 2048
        const int D_FILL = (2*NE)/256;    // 512
        for (int it = bid; it < D_NODE + D_FILL; it += nblk) {
            if (it < D_NODE) {
                const int node = it * 4 + wave;
                const float a0 = p.a_ws[node*2], a1 = p.a_ws[node*2+1];
                const float4* wv0 = (const float4*)p.Wv;
                const float4* wv1 = (const float4*)(p.Wv + DK);
                const float4* g4 = (const float4*)p.ln_g;
                const float4* b4 = (const float4*)p.ln_b;
                float4 W0[2], W1[2], Gg[2], Bb[2];
                #pragma unroll
                for (int k = 0; k < 2; k++) {
                    int c4 = lane*2 + k;
                    W0[k] = wv0[c4]; W1[k] = wv1[c4]; Gg[k] = g4[c4]; Bb[k] = b4[c4];
                }
                float s0=0.f, s1=0.f, q00=0.f, q01=0.f, q11=0.f;
                #pragma unroll
                for (int k = 0; k < 2; k++) {
                    const float* u = (const float*)&W0[k];
                    const float* v = (const float*)&W1[k];
                    #pragma unroll
                    for (int j = 0; j < 4; j++) {
                        s0 += u[j]; s1 += v[j];
                        q00 += u[j]*u[j]; q01 += u[j]*v[j]; q11 += v[j]*v[j];
                    }
                }
                #pragma unroll
                for (int off = 1; off < 64; off <<= 1) {
                    s0 += __shfl_xor(s0,off); s1 += __shfl_xor(s1,off);
                    q00 += __shfl_xor(q00,off); q01 += __shfl_xor(q01,off); q11 += __shfl_xor(q11,off);
                }
                const float mean = (a0*s0 + a1*s1) * (1.f/DK);
                const float msq  = (a0*a0*q00 + 2.f*a0*a1*q01 + a1*a1*q11) * (1.f/DK);
                const float inv  = rsqrtf(msq - mean*mean + 1e-5f);
                const float alpha = p.prelu_a[0];
                #pragma unroll
                for (int k = 0; k < 2; k++) {
                    int c4 = lane*2 + k;
                    const float* u = (const float*)&W0[k];
                    const float* v = (const float*)&W1[k];
                    const float* gf = (const float*)&Gg[k];
                    const float* bf = (const float*)&Bb[k];
                    #pragma unroll
                    for (int j = 0; j < 4; j++) {
                        float od = a0*u[j] + a1*v[j];
                        float nd = (od - mean) * inv * gf[j] + bf[j];
                        t[wave][c4*4 + j] = (nd >= 0.f) ? nd : alpha*nd;
                    }
                }
                __syncthreads();
                const int c = lane & 31, half = lane >> 5;
                const float* tp = t[wave] + half*256;
                const float* mw = p.mlp_W + half*256*HC + c;
                float partl = 0.f;
                for (int d = 0; d < 256; d++) partl += tp[d] * mw[d*HC];
                partl += __shfl_down(partl, 32);
                float hc = 0.f;
                if (lane < 32) { hc = partl + p.mlp_b[c]; hbuf[wave][c] = hc; }
                __syncthreads();
                float sp = (lane < 32) ? hc * p.np_W[c] : 0.f;
                #pragma unroll
                for (int off = 16; off > 0; off >>= 1) sp += __shfl_down(sp, off);
                if (lane == 0) p.ns[node] = sp + p.np_b[0];
                const float* hb_ = hbuf[wave];
                if (lane < 32) {
                    float acc2 = p.body_b[c];
                    #pragma unroll 8
                    for (int cp = 0; cp < HC; cp++) acc2 += hb_[cp] * p.body_W[cp*HC + c];
                    p.hlb[(size_t)node*HC + c] = acc2;
                } else {
                    float acc2 = p.face_b[c];
                    #pragma unroll 8
                    for (int cp = 0; cp < HC; cp++) acc2 += hb_[cp] * p.face_W[cp*HC + c];
                    p.hlf[(size_t)node*HC + c] = acc2;
                }
            } else {
                const int e = (it - D_NODE) * 256 + tid;
                if (e < NE) {
                    int s = p.eib[e], d = p.eib[NE + e];
                    int pos = atomicAdd(&p.cursor[d], 1);
                    p.esrc[pos] = s; p.edst[pos] = d;
                } else {
                    int e2 = e - NE;
                    int s = p.eif[e2], d = p.eif[NE + e2];
                    int pos = atomicAdd(&p.cursor[NN + d], 1);
                    p.esrc[NE + pos] = s; p.edst[NE + pos] = d;
                }
            }
        }
    }
    g.sync();

    // ===== Phase E: edge cosines in CSR order (2 edges / wave) =====
    {
        const int E_BODY = NE/8, E_TOT = NE/4;   // 8 edges per block-iter
        for (int it = bid; it < E_TOT; it += nblk) {
            float dot0, dot1;
            int i0;
            if (it < E_BODY) {
                i0 = it*8 + wave*2;
                const int s0 = p.esrc[i0], d0 = p.edst[i0], s1 = p.esrc[i0+1], d1 = p.edst[i0+1];
                const int4* A  = (const int4*)(p.vnb + (size_t)s0 * (DB/4));
                const int4* Bp = (const int4*)(p.vnb + (size_t)d0 * (DB/4));
                const int4* C  = (const int4*)(p.vnb + (size_t)s1 * (DB/4));
                const int4* E  = (const int4*)(p.vnb + (size_t)d1 * (DB/4));
                int4 a0 = A[lane],  a1 = A[lane+64];
                int4 b0 = Bp[lane], b1 = Bp[lane+64];
                int4 c0 = C[lane],  c1 = C[lane+64];
                int4 e0 = E[lane],  e1 = E[lane+64];
                dot0 = fp8dot16(a0,b0) + fp8dot16(a1,b1);
                dot1 = fp8dot16(c0,e0) + fp8dot16(c1,e1);
            } else {
                i0 = NE + (it - E_BODY)*8 + wave*2;
                const int s0 = p.esrc[i0], d0 = p.edst[i0], s1 = p.esrc[i0+1], d1 = p.edst[i0+1];
                const int2* A  = (const int2*)(p.vnf + (size_t)s0 * (DF/4));
                const int2* Bp = (const int2*)(p.vnf + (size_t)d0 * (DF/4));
                const int2* C  = (const int2*)(p.vnf + (size_t)s1 * (DF/4));
                const int2* E  = (const int2*)(p.vnf + (size_t)d1 * (DF/4));
                int2 a = A[lane], b = Bp[lane], c = C[lane], e = E[lane];
                dot0 = fp8dot4((unsigned)a.x,(unsigned)b.x) + fp8dot4((unsigned)a.y,(unsigned)b.y);
                dot1 = fp8dot4((unsigned)c.x,(unsigned)e.x) + fp8dot4((unsigned)c.y,(unsigned)e.y);
            }
            #pragma unroll
            for (int off = 1; off < 64; off <<= 1) {
                dot0 += __shfl_xor(dot0, off);
                dot1 += __shfl_xor(dot1, off);
            }
            if (lane == 0) ((float2*)p.w)[i0 >> 1] = make_float2(dot0, dot1);
        }
    }
    g.sync();

    // ===== Phase F: gather + projections + final =====
    for (int it = bid; it < NN/4; it += nblk) {
        const int node = it * 4 + wave;
        const bool bodyhalf = lane < 32;
        const int c = lane & 31;
        const int sbase = bodyhalf ? 0 : (NN + 1);
        const int eofs = bodyhalf ? 0 : NE;
        const float* hl = bodyhalf ? p.hlb : p.hlf;
        const int s0 = p.starts[sbase + node], s1 = p.starts[sbase + node + 1];
        float acc = 0.f;
        for (int i = s0; i < s1; i++) {
            float wv = p.w[eofs + i];
            int s = p.esrc[eofs + i];
            acc += wv * hl[(size_t)s * HC + c];
        }
        float pr = acc * (bodyhalf ? p.pb_W : p.pf_W)[c];
        #pragma unroll
        for (int off = 16; off > 0; off >>= 1) pr += __shfl_down(pr, off);
        float tot = __shfl(pr, 0) + __shfl(pr, 32);
        if (lane == 0) p.out[node] = p.ns[node] + tot + p.pb_b[0] + p.pf_b[0];
    }
}

// ===================== fallback multi-kernel path (R3, proven) =====================
__global__ __launch_bounds__(256) void fused1_kernel(Params p) {
    __shared__ float red[4];
    __shared__ float s_inv;
    __shared__ float2 xs[NG];
    __shared__ float pm[4][4];
    __shared__ float sm4[4];
    const int bid = blockIdx.x, tid = threadIdx.x;
    const int lane = tid & 63, wave = tid >> 6;
    if (bid < 2*NN) {
        const bool body = bid < NN;
        const int node = body ? bid : bid - NN;
        const int D = body ? DB : DF;
        const float4* r4 = (const float4*)((body ? p.vb : p.vf) + (size_t)node * D);
        unsigned* orow = (body ? p.vnb : p.vnf) + (size_t)node * (D/4);
        float ss = 0.f;
        for (int c = tid; c < D/4; c += 256) {
            float4 q = r4[c];
            ss += q.x*q.x + q.y*q.y + q.z*q.z + q.w*q.w;
        }
        #pragma unroll
        for (int off = 32; off > 0; off >>= 1) ss += __shfl_down(ss, off);
        if (lane == 0) red[wave] = ss;
        __syncthreads();
        if (tid == 0) s_inv = rsqrtf(red[0]+red[1]+red[2]+red[3] + 1e-8f);
        __syncthreads();
        const float inv = s_inv;
        for (int c = tid; c < D/4; c += 256) {
            float4 q = r4[c];
            orow[c] = pack4_fp8(q.x*inv, q.y*inv, q.z*inv, q.w*inv);
        }
    } else if (bid < 2*NN + 512) {
        const int e = (bid - 2*NN) * 256 + tid;
        if (e < NE) atomicAdd(&p.counts[p.eib[NE + e]], 1);
        else        atomicAdd(&p.counts[NN + p.eif[NE + (e - NE)]], 1);
    } else {
        const int gg = bid - (2*NN + 512);
        xs[tid] = ((const float2*)p.x)[gg*NG + tid];
        const int d = tid * 2;
        float q0a = p.Wq[d],    q0b = p.Wq[d+1];
        float q1a = p.Wq[DK+d], q1b = p.Wq[DK+d+1];
        float k0a = p.Wk[d],    k0b = p.Wk[d+1];
        float k1a = p.Wk[DK+d], k1b = p.Wk[DK+d+1];
        float m00 = q0a*k0a + q0b*k0b;
        float m01 = q0a*k1a + q0b*k1b;
        float m10 = q1a*k0a + q1b*k0b;
        float m11 = q1a*k1a + q1b*k1b;
        #pragma unroll
        for (int off = 32; off > 0; off >>= 1) {
            m00 += __shfl_down(m00,off); m01 += __shfl_down(m01,off);
            m10 += __shfl_down(m10,off); m11 += __shfl_down(m11,off);
        }
        if (lane == 0) { pm[wave][0]=m00; pm[wave][1]=m01; pm[wave][2]=m10; pm[wave][3]=m11; }
        __syncthreads();
        if (tid < 4) sm4[tid] = pm[0][tid] + pm[1][tid] + pm[2][tid] + pm[3][tid];
        __syncthreads();
        const float scale = 0.04419417382415922f;
        const float2 xi = xs[tid];
        const float u0 = (xi.x*sm4[0] + xi.y*sm4[2]) * scale;
        const float u1 = (xi.x*sm4[1] + xi.y*sm4[3]) * scale;
        float m = -1e30f;
        for (int j = 0; j < NG; j++) m = fmaxf(m, u0*xs[j].x + u1*xs[j].y);
        float S = 0.f, a0 = 0.f, a1 = 0.f;
        for (int j = 0; j < NG; j++) {
            float2 xj = xs[j];
            float pr = __expf(u0*xj.x + u1*xj.y - m);
            S += pr; a0 += pr*xj.x; a1 += pr*xj.y;
        }
        const float invS = 1.f / S;
        ((float2*)p.a_ws)[gg*NG + tid] = make_float2(a0*invS, a1*invS);
    }
}

__global__ __launch_bounds__(256) void fused2_kernel(Params p) {
    __shared__ int part[256];
    __shared__ float t[4][DK];
    __shared__ float hbuf[4][HC];
    const int bid = blockIdx.x, tid = threadIdx.x;
    if (bid < 2) {
        const int cbase = bid * NN;
        const int sbase = bid * (NN + 1);
        int loc[32];
        int sum = 0;
        #pragma unroll
        for (int j = 0; j < 32; j++) { loc[j] = p.counts[cbase + tid*32 + j]; sum += loc[j]; }
        part[tid] = sum;
        __syncthreads();
        for (int off = 1; off < 256; off <<= 1) {
            int v = (tid >= off) ? part[tid - off] : 0;
            __syncthreads();
            part[tid] += v;
            __syncthreads();
        }
        int run = (tid == 0) ? 0 : part[tid - 1];
        #pragma unroll
        for (int j = 0; j < 32; j++) {
            p.starts[sbase + tid*32 + j] = run;
            p.cursor[cbase + tid*32 + j] = run;
            run += loc[j];
        }
        if (tid == 255) p.starts[sbase + NN] = run;
        return;
    }
    const int wave = tid >> 6, lane = tid & 63;
    const int node = (bid - 2) * 4 + wave;
    const float a0 = p.a_ws[node*2], a1 = p.a_ws[node*2+1];
    const float4* wv0 = (const float4*)p.Wv;
    const float4* wv1 = (const float4*)(p.Wv + DK);
    const float4* g4 = (const float4*)p.ln_g;
    const float4* b4 = (const float4*)p.ln_b;
    float4 W0[2], W1[2], Gg[2], Bb[2];
    #pragma unroll
    for (int k = 0; k < 2; k++) {
        int c4 = lane*2 + k;
        W0[k] = wv0[c4]; W1[k] = wv1[c4]; Gg[k] = g4[c4]; Bb[k] = b4[c4];
    }
    float s0=0.f, s1=0.f, q00=0.f, q01=0.f, q11=0.f;
    #pragma unroll
    for (int k = 0; k < 2; k++) {
        const float* u = (const float*)&W0[k];
        const float* v = (const float*)&W1[k];
        #pragma unroll
        for (int j = 0; j < 4; j++) {
            s0 += u[j]; s1 += v[j];
            q00 += u[j]*u[j]; q01 += u[j]*v[j]; q11 += v[j]*v[j];
        }
    }
    #pragma unroll
    for (int off = 1; off < 64; off <<= 1) {
        s0 += __shfl_xor(s0,off); s1 += __shfl_xor(s1,off);
        q00 += __shfl_xor(q00,off); q01 += __shfl_xor(q01,off); q11 += __shfl_xor(q11,off);
    }
    const float mean = (a0*s0 + a1*s1) * (1.f/DK);
    const float msq  = (a0*a0*q00 + 2.f*a0*a1*q01 + a1*a1*q11) * (1.f/DK);
    const float inv  = rsqrtf(msq - mean*mean + 1e-5f);
    const float alpha = p.prelu_a[0];
    #pragma unroll
    for (int k = 0; k < 2; k++) {
        int c4 = lane*2 + k;
        const float* u = (const float*)&W0[k];
        const float* v = (const float*)&W1[k];
        const float* gf = (const float*)&Gg[k];
        const float* bf = (const float*)&Bb[k];
        #pragma unroll
        for (int j = 0; j < 4; j++) {
            float od = a0*u[j] + a1*v[j];
            float nd = (od - mean) * inv * gf[j] + bf[j];
            t[wave][c4*4 + j] = (nd >= 0.f) ? nd : alpha*nd;
        }
    }
    __syncthreads();
    const int c = lane & 31, half = lane >> 5;
    const float* tp = t[wave] + half*256;
    const float* mw = p.mlp_W + half*256*HC + c;
    float partl = 0.f;
    for (int d = 0; d < 256; d++) partl += tp[d] * mw[d*HC];
    partl += __shfl_down(partl, 32);
    float hc = 0.f;
    if (lane < 32) { hc = partl + p.mlp_b[c]; hbuf[wave][c] = hc; }
    __syncthreads();
    float sp = (lane < 32) ? hc * p.np_W[c] : 0.f;
    #pragma unroll
    for (int off = 16; off > 0; off >>= 1) sp += __shfl_down(sp, off);
    if (lane == 0) p.ns[node] = sp + p.np_b[0];
    const float* hb_ = hbuf[wave];
    if (lane < 32) {
        float acc2 = p.body_b[c];
        #pragma unroll 8
        for (int cp = 0; cp < HC; cp++) acc2 += hb_[cp] * p.body_W[cp*HC + c];
        p.hlb[(size_t)node*HC + c] = acc2;
    } else {
        float acc2 = p.face_b[c];
        #pragma unroll 8
        for (int cp = 0; cp < HC; cp++) acc2 += hb_[cp] * p.face_W[cp*HC + c];
        p.hlf[(size_t)node*HC + c] = acc2;
    }
}

__global__ __launch_bounds__(256) void fill_kernel(Params p) {
    const int e = blockIdx.x * 256 + threadIdx.x;
    if (e < NE) {
        int s = p.eib[e], d = p.eib[NE + e];
        int pos = atomicAdd(&p.cursor[d], 1);
        p.esrc[pos] = s; p.edst[pos] = d;
    } else {
        int e2 = e - NE;
        int s = p.eif[e2], d = p.eif[NE + e2];
        int pos = atomicAdd(&p.cursor[NN + d], 1);
        p.esrc[NE + pos] = s; p.edst[NE + pos] = d;
    }
}

__global__ __launch_bounds__(256) void wdot_kernel(Params p) {
    const int wave = threadIdx.x >> 6, lane = threadIdx.x & 63;
    const int base = (blockIdx.x * 4 + wave) * 2;
    float dot0, dot1;
    int i0 = base;
    if (base < NE) {
        const int s0 = p.esrc[i0], d0 = p.edst[i0], s1 = p.esrc[i0+1], d1 = p.edst[i0+1];
        const int4* A  = (const int4*)(p.vnb + (size_t)s0 * (DB/4));
        const int4* Bp = (const int4*)(p.vnb + (size_t)d0 * (DB/4));
        const int4* C  = (const int4*)(p.vnb + (size_t)s1 * (DB/4));
        const int4* E  = (const int4*)(p.vnb + (size_t)d1 * (DB/4));
        int4 a0 = A[lane],  a1 = A[lane+64];
        int4 b0 = Bp[lane], b1 = Bp[lane+64];
        int4 c0 = C[lane],  c1 = C[lane+64];
        int4 e0 = E[lane],  e1 = E[lane+64];
        dot0 = fp8dot16(a0,b0) + fp8dot16(a1,b1);
        dot1 = fp8dot16(c0,e0) + fp8dot16(c1,e1);
    } else {
        const int s0 = p.esrc[i0], d0 = p.edst[i0], s1 = p.esrc[i0+1], d1 = p.edst[i0+1];
        const int2* A  = (const int2*)(p.vnf + (size_t)s0 * (DF/4));
        const int2* Bp = (const int2*)(p.vnf + (size_t)d0 * (DF/4));
        const int2* C  = (const int2*)(p.vnf + (size_t)s1 * (DF/4));
        const int2* E  = (const int2*)(p.vnf + (size_t)d1 * (DF/4));
        int2 a = A[lane], b = Bp[lane], c = C[lane], e = E[lane];
        dot0 = fp8dot4((unsigned)a.x,(unsigned)b.x) + fp8dot4((unsigned)a.y,(unsigned)b.y);
        dot1 = fp8dot4((unsigned)c.x,(unsigned)e.x) + fp8dot4((unsigned)c.y,(unsigned)e.y);
    }
    #pragma unroll
    for (int off = 1; off < 64; off <<= 1) {
        dot0 += __shfl_xor(dot0, off);
        dot1 += __shfl_xor(dot1, off);
    }
    if (lane == 0) ((float2*)p.w)[i0 >> 1] = make_float2(dot0, dot1);
}

__global__ __launch_bounds__(256) void gather_kernel(Params p) {
    const int wave = threadIdx.x >> 6, lane = threadIdx.x & 63;
    const int node = blockIdx.x * 4 + wave;
    const bool bodyhalf = lane < 32;
    const int c = lane & 31;
    const int sbase = bodyhalf ? 0 : (NN + 1);
    const int eofs = bodyhalf ? 0 : NE;
    const float* hl = bodyhalf ? p.hlb : p.hlf;
    const int s0 = p.starts[sbase + node], s1 = p.starts[sbase + node + 1];
    float acc = 0.f;
    for (int i = s0; i < s1; i++) {
        float wv = p.w[eofs + i];
        int s = p.esrc[eofs + i];
        acc += wv * hl[(size_t)s * HC + c];
    }
    float pr = acc * (bodyhalf ? p.pb_W : p.pf_W)[c];
    #pragma unroll
    for (int off = 16; off > 0; off >>= 1) pr += __shfl_down(pr, off);
    float tot = __shfl(pr, 0) + __shfl(pr, 32);
    if (lane == 0) p.out[node] = p.ns[node] + tot + p.pb_b[0] + p.pf_b[0];
}

extern "C" void kernel_launch(void* const* d_in, const int* in_sizes, int n_in,
                              void* d_out, int out_size, void* d_ws, size_t ws_size,
                              hipStream_t stream) {
    char* ws = (char*)d_ws;
    size_t off = 0;
    auto alloc = [&](size_t bytes) { void* pp = ws + off; off += (bytes + 15) & ~size_t(15); return pp; };

    Params p;
    p.vb      = (const float*)d_in[1];
    p.vf      = (const float*)d_in[2];
    p.x       = (const float*)d_in[0];
    p.Wq      = (const float*)d_in[3];
    p.Wk      = (const float*)d_in[4];
    p.Wv      = (const float*)d_in[5];
    p.ln_g    = (const float*)d_in[6];
    p.ln_b    = (const float*)d_in[7];
    p.prelu_a = (const float*)d_in[8];
    p.mlp_W   = (const float*)d_in[9];
    p.mlp_b   = (const float*)d_in[10];
    p.np_W    = (const float*)d_in[11];
    p.np_b    = (const float*)d_in[12];
    p.body_W  = (const float*)d_in[13];
    p.body_b  = (const float*)d_in[14];
    p.face_W  = (const float*)d_in[15];
    p.face_b  = (const float*)d_in[16];
    p.pb_W    = (const float*)d_in[17];
    p.pb_b    = (const float*)d_in[18];
    p.pf_W    = (const float*)d_in[19];
    p.pf_b    = (const float*)d_in[20];
    p.eib     = (const int*)d_in[21];
    p.eif     = (const int*)d_in[22];
    p.vnb     = (unsigned*)alloc((size_t)NN*(DB/4)*4);   // 16 MB fp8
    p.vnf     = (unsigned*)alloc((size_t)NN*(DF/4)*4);   //  4 MB fp8
    p.a_ws    = (float*)alloc((size_t)NN*2*4);
    p.ns      = (float*)alloc((size_t)NN*4);
    p.hlb     = (float*)alloc((size_t)NN*HC*4);
    p.hlf     = (float*)alloc((size_t)NN*HC*4);
    p.w       = (float*)alloc((size_t)2*NE*4);
    p.counts  = (int*)alloc((size_t)2*NN*4);
    p.starts  = (int*)alloc((size_t)2*(NN+1)*4);
    p.cursor  = (int*)alloc((size_t)2*NN*4);
    p.esrc    = (int*)alloc((size_t)2*NE*4);
    p.edst    = (int*)alloc((size_t)2*NE*4);
    p.out     = (float*)d_out;

    void* args[] = { &p };
    hipError_t err = hipLaunchCooperativeKernel((void*)mega_kernel, dim3(GRID),
                                                dim3(256), args, 0, stream);
    if (err != hipSuccess) {
        // Fallback: proven multi-kernel path (R3). Same math, same buffers.
        hipMemsetAsync(p.counts, 0, (size_t)2*NN*4, stream);
        fused1_kernel<<<2*NN + 512 + NB, 256, 0, stream>>>(p);
        fused2_kernel<<<2 + NN/4, 256, 0, stream>>>(p);
        fill_kernel<<<2*NE/256, 256, 0, stream>>>(p);
        wdot_kernel<<<2*NE/8, 256, 0, stream>>>(p);
        gather_kernel<<<NN/4, 256, 0, stream>>>(p);
    }
}

// Round 6
// 249.794 us; speedup vs baseline: 2.4298x; 2.4298x over previous
//
#include <hip/hip_runtime.h>

#define NN 8192     // nodes
#define NB 32       // graphs
#define NG 256      // nodes per graph
#define NE 65536    // edges per graph type
#define DK 512
#define HC 32
#define DB 2048     // body visual dim
#define DF 512      // face visual dim

typedef float v2f __attribute__((ext_vector_type(2)));

#if __has_builtin(__builtin_amdgcn_cvt_pk_f32_fp8) && __has_builtin(__builtin_amdgcn_cvt_pk_fp8_f32)
#define HW_FP8 1
#else
#define HW_FP8 0
#endif

// ---- fp8 e4m3fn helpers (manual fallback only if builtins missing) ----
__device__ __forceinline__ float fp8_dec(unsigned u) {
    unsigned e = (u >> 3) & 15u, m = u & 7u, s = u & 0x80u;
    float v = e ? __uint_as_float(((e + 120u) << 23) | (m << 20))
                : (float)m * 0.001953125f;
    return s ? -v : v;
}
__device__ __forceinline__ unsigned fp8_enc(float x) {
    unsigned sb = (__float_as_uint(x) >> 24) & 0x80u;
    float a = fabsf(x);
    if (a >= 448.f) return sb | 0x7Eu;
    if (a < 0.015625f) {
        int c = (int)rintf(a * 512.f);
        if (c > 7) return sb | 0x08u;
        return sb | (unsigned)c;
    }
    int ex; (void)frexpf(a, &ex);
    float p = ldexpf(a, 1 - ex);
    int m = (int)rintf((p - 1.f) * 8.f);
    int e = ex - 1 + 7;
    if (m == 8) { m = 0; e++; }
    if (e >= 16) return sb | 0x7Eu;
    return sb | (unsigned)(e << 3) | (unsigned)m;
}
__device__ __forceinline__ unsigned pack4_fp8(float x, float y, float z, float w) {
#if HW_FP8
    int u = __builtin_amdgcn_cvt_pk_fp8_f32(x, y, 0, false);
    u = __builtin_amdgcn_cvt_pk_fp8_f32(z, w, u, true);
    return (unsigned)u;
#else
    return fp8_enc(x) | (fp8_enc(y) << 8) | (fp8_enc(z) << 16) | (fp8_enc(w) << 24);
#endif
}
__device__ __forceinline__ float fp8dot4(unsigned a, unsigned b) {
#if HW_FP8
    v2f al = __builtin_amdgcn_cvt_pk_f32_fp8((int)a, false);
    v2f ah = __builtin_amdgcn_cvt_pk_f32_fp8((int)a, true);
    v2f bl = __builtin_amdgcn_cvt_pk_f32_fp8((int)b, false);
    v2f bh = __builtin_amdgcn_cvt_pk_f32_fp8((int)b, true);
    return al.x*bl.x + al.y*bl.y + ah.x*bh.x + ah.y*bh.y;
#else
    float s = 0.f;
    #pragma unroll
    for (int j = 0; j < 4; j++)
        s += fp8_dec((a >> (8*j)) & 255u) * fp8_dec((b >> (8*j)) & 255u);
    return s;
#endif
}
__device__ __forceinline__ float fp8dot16(int4 a, int4 b) {
    return fp8dot4((unsigned)a.x, (unsigned)b.x) + fp8dot4((unsigned)a.y, (unsigned)b.y)
         + fp8dot4((unsigned)a.z, (unsigned)b.z) + fp8dot4((unsigned)a.w, (unsigned)b.w);
}

struct Params {
    const float *vb, *vf, *x, *Wq, *Wk, *Wv, *ln_g, *ln_b, *prelu_a;
    const float *mlp_W, *mlp_b, *np_W, *np_b, *body_W, *body_b, *face_W, *face_b;
    const float *pb_W, *pb_b, *pf_W, *pf_b;
    const int *eib, *eif;
    unsigned *vnb, *vnf;
    float *a_ws, *ns, *hlb, *hlf, *w;
    int *counts, *starts, *cursor, *esrc, *edst;
    float *out;
};

// ===== L1: norm->fp8 (wave-per-row, barrier-free) + edge count + attention =====
// blocks [0, NN/4)            : body rows, 1 row / wave (8 float4 / lane)
// blocks [NN/4, NN/2)         : face rows, 1 row / wave (2 float4 / lane)
// blocks [NN/2, NN/2+512)     : degree count
// blocks [NN/2+512, +NB)      : rank-2 attention
__global__ __launch_bounds__(256) void fused1_kernel(Params p) {
    __shared__ float2 xs[NG];
    __shared__ float pm[4][4];
    __shared__ float sm4[4];
    const int bid = blockIdx.x, tid = threadIdx.x;
    const int lane = tid & 63, wave = tid >> 6;
    const int B_BODY = NN/4, B_FACE = NN/4, B_CNT = (2*NE)/256;

    if (bid < B_BODY) {
        const int node = bid * 4 + wave;
        const float4* r4 = (const float4*)(p.vb + (size_t)node * DB);
        float4 v[8];
        #pragma unroll
        for (int k = 0; k < 8; k++) v[k] = r4[lane + 64*k];
        float ss = 0.f;
        #pragma unroll
        for (int k = 0; k < 8; k++)
            ss += v[k].x*v[k].x + v[k].y*v[k].y + v[k].z*v[k].z + v[k].w*v[k].w;
        #pragma unroll
        for (int off = 1; off < 64; off <<= 1) ss += __shfl_xor(ss, off);
        const float inv = rsqrtf(ss + 1e-8f);
        unsigned* orow = p.vnb + (size_t)node * (DB/4);
        #pragma unroll
        for (int k = 0; k < 8; k++)
            orow[lane + 64*k] = pack4_fp8(v[k].x*inv, v[k].y*inv, v[k].z*inv, v[k].w*inv);
    } else if (bid < B_BODY + B_FACE) {
        const int node = (bid - B_BODY) * 4 + wave;
        const float4* r4 = (const float4*)(p.vf + (size_t)node * DF);
        float4 a = r4[lane], b = r4[lane + 64];
        float ss = a.x*a.x + a.y*a.y + a.z*a.z + a.w*a.w
                 + b.x*b.x + b.y*b.y + b.z*b.z + b.w*b.w;
        #pragma unroll
        for (int off = 1; off < 64; off <<= 1) ss += __shfl_xor(ss, off);
        const float inv = rsqrtf(ss + 1e-8f);
        unsigned* orow = p.vnf + (size_t)node * (DF/4);
        orow[lane]      = pack4_fp8(a.x*inv, a.y*inv, a.z*inv, a.w*inv);
        orow[lane + 64] = pack4_fp8(b.x*inv, b.y*inv, b.z*inv, b.w*inv);
    } else if (bid < B_BODY + B_FACE + B_CNT) {
        const int e = (bid - B_BODY - B_FACE) * 256 + tid;
        if (e < NE) atomicAdd(&p.counts[p.eib[NE + e]], 1);
        else        atomicAdd(&p.counts[NN + p.eif[NE + (e - NE)]], 1);
    } else {
        const int gg = bid - (B_BODY + B_FACE + B_CNT);
        xs[tid] = ((const float2*)p.x)[gg*NG + tid];
        const int d = tid * 2;
        float q0a = p.Wq[d],    q0b = p.Wq[d+1];
        float q1a = p.Wq[DK+d], q1b = p.Wq[DK+d+1];
        float k0a = p.Wk[d],    k0b = p.Wk[d+1];
        float k1a = p.Wk[DK+d], k1b = p.Wk[DK+d+1];
        float m00 = q0a*k0a + q0b*k0b;
        float m01 = q0a*k1a + q0b*k1b;
        float m10 = q1a*k0a + q1b*k0b;
        float m11 = q1a*k1a + q1b*k1b;
        #pragma unroll
        for (int off = 32; off > 0; off >>= 1) {
            m00 += __shfl_down(m00,off); m01 += __shfl_down(m01,off);
            m10 += __shfl_down(m10,off); m11 += __shfl_down(m11,off);
        }
        if (lane == 0) { pm[wave][0]=m00; pm[wave][1]=m01; pm[wave][2]=m10; pm[wave][3]=m11; }
        __syncthreads();
        if (tid < 4) sm4[tid] = pm[0][tid] + pm[1][tid] + pm[2][tid] + pm[3][tid];
        __syncthreads();
        const float scale = 0.04419417382415922f;  // 1/sqrt(512)
        const float2 xi = xs[tid];
        const float u0 = (xi.x*sm4[0] + xi.y*sm4[2]) * scale;
        const float u1 = (xi.x*sm4[1] + xi.y*sm4[3]) * scale;
        float m = -1e30f;
        for (int j = 0; j < NG; j++) m = fmaxf(m, u0*xs[j].x + u1*xs[j].y);
        float S = 0.f, a0 = 0.f, a1 = 0.f;
        for (int j = 0; j < NG; j++) {
            float2 xj = xs[j];
            float pr = __expf(u0*xj.x + u1*xj.y - m);
            S += pr; a0 += pr*xj.x; a1 += pr*xj.y;
        }
        const float invS = 1.f / S;
        ((float2*)p.a_ws)[gg*NG + tid] = make_float2(a0*invS, a1*invS);
    }
}

// ===== L2: CSR scan (blocks 0,1) + per-node MLP pipeline =====
__global__ __launch_bounds__(256) void fused2_kernel(Params p) {
    __shared__ int part[256];
    __shared__ float t[4][DK];
    __shared__ float hbuf[4][HC];
    const int bid = blockIdx.x, tid = threadIdx.x;
    if (bid < 2) {
        const int cbase = bid * NN;
        const int sbase = bid * (NN + 1);
        int loc[32];
        int sum = 0;
        #pragma unroll
        for (int j = 0; j < 32; j++) { loc[j] = p.counts[cbase + tid*32 + j]; sum += loc[j]; }
        part[tid] = sum;
        __syncthreads();
        for (int off = 1; off < 256; off <<= 1) {
            int v = (tid >= off) ? part[tid - off] : 0;
            __syncthreads();
            part[tid] += v;
            __syncthreads();
        }
        int run = (tid == 0) ? 0 : part[tid - 1];
        #pragma unroll
        for (int j = 0; j < 32; j++) {
            p.starts[sbase + tid*32 + j] = run;
            p.cursor[cbase + tid*32 + j] = run;
            run += loc[j];
        }
        if (tid == 255) p.starts[sbase + NN] = run;
        return;
    }
    const int wave = tid >> 6, lane = tid & 63;
    const int node = (bid - 2) * 4 + wave;
    const float a0 = p.a_ws[node*2], a1 = p.a_ws[node*2+1];
    const float4* wv0 = (const float4*)p.Wv;
    const float4* wv1 = (const float4*)(p.Wv + DK);
    const float4* g4 = (const float4*)p.ln_g;
    const float4* b4 = (const float4*)p.ln_b;
    float4 W0[2], W1[2], Gg[2], Bb[2];
    #pragma unroll
    for (int k = 0; k < 2; k++) {
        int c4 = lane*2 + k;
        W0[k] = wv0[c4]; W1[k] = wv1[c4]; Gg[k] = g4[c4]; Bb[k] = b4[c4];
    }
    float s0=0.f, s1=0.f, q00=0.f, q01=0.f, q11=0.f;
    #pragma unroll
    for (int k = 0; k < 2; k++) {
        const float* u = (const float*)&W0[k];
        const float* v = (const float*)&W1[k];
        #pragma unroll
        for (int j = 0; j < 4; j++) {
            s0 += u[j]; s1 += v[j];
            q00 += u[j]*u[j]; q01 += u[j]*v[j]; q11 += v[j]*v[j];
        }
    }
    #pragma unroll
    for (int off = 1; off < 64; off <<= 1) {
        s0 += __shfl_xor(s0,off); s1 += __shfl_xor(s1,off);
        q00 += __shfl_xor(q00,off); q01 += __shfl_xor(q01,off); q11 += __shfl_xor(q11,off);
    }
    const float mean = (a0*s0 + a1*s1) * (1.f/DK);
    const float msq  = (a0*a0*q00 + 2.f*a0*a1*q01 + a1*a1*q11) * (1.f/DK);
    const float inv  = rsqrtf(msq - mean*mean + 1e-5f);
    const float alpha = p.prelu_a[0];
    #pragma unroll
    for (int k = 0; k < 2; k++) {
        int c4 = lane*2 + k;
        const float* u = (const float*)&W0[k];
        const float* v = (const float*)&W1[k];
        const float* gf = (const float*)&Gg[k];
        const float* bf = (const float*)&Bb[k];
        #pragma unroll
        for (int j = 0; j < 4; j++) {
            float od = a0*u[j] + a1*v[j];
            float nd = (od - mean) * inv * gf[j] + bf[j];
            t[wave][c4*4 + j] = (nd >= 0.f) ? nd : alpha*nd;
        }
    }
    __syncthreads();
    const int c = lane & 31, half = lane >> 5;
    const float* tp = t[wave] + half*256;
    const float* mw = p.mlp_W + half*256*HC + c;
    float partl = 0.f;
    for (int d = 0; d < 256; d++) partl += tp[d] * mw[d*HC];
    partl += __shfl_down(partl, 32);
    float hc = 0.f;
    if (lane < 32) { hc = partl + p.mlp_b[c]; hbuf[wave][c] = hc; }
    __syncthreads();
    float sp = (lane < 32) ? hc * p.np_W[c] : 0.f;
    #pragma unroll
    for (int off = 16; off > 0; off >>= 1) sp += __shfl_down(sp, off);
    if (lane == 0) p.ns[node] = sp + p.np_b[0];
    const float* hb_ = hbuf[wave];
    if (lane < 32) {
        float acc2 = p.body_b[c];
        #pragma unroll 8
        for (int cp = 0; cp < HC; cp++) acc2 += hb_[cp] * p.body_W[cp*HC + c];
        p.hlb[(size_t)node*HC + c] = acc2;
    } else {
        float acc2 = p.face_b[c];
        #pragma unroll 8
        for (int cp = 0; cp < HC; cp++) acc2 += hb_[cp] * p.face_W[cp*HC + c];
        p.hlf[(size_t)node*HC + c] = acc2;
    }
}

// ===== L3: CSR fill =====
__global__ __launch_bounds__(256) void fill_kernel(Params p) {
    const int e = blockIdx.x * 256 + threadIdx.x;
    if (e < NE) {
        int s = p.eib[e], d = p.eib[NE + e];
        int pos = atomicAdd(&p.cursor[d], 1);
        p.esrc[pos] = s; p.edst[pos] = d;
    } else {
        int e2 = e - NE;
        int s = p.eif[e2], d = p.eif[NE + e2];
        int pos = atomicAdd(&p.cursor[NN + d], 1);
        p.esrc[NE + pos] = s; p.edst[NE + pos] = d;
    }
}

// ===== L4: edge cosines in CSR order (2 edges / wave) =====
__global__ __launch_bounds__(256) void wdot_kernel(Params p) {
    const int wave = threadIdx.x >> 6, lane = threadIdx.x & 63;
    const int base = (blockIdx.x * 4 + wave) * 2;
    float dot0, dot1;
    int i0 = base;
    if (base < NE) {
        const int s0 = p.esrc[i0], d0 = p.edst[i0], s1 = p.esrc[i0+1], d1 = p.edst[i0+1];
        const int4* A  = (const int4*)(p.vnb + (size_t)s0 * (DB/4));
        const int4* Bp = (const int4*)(p.vnb + (size_t)d0 * (DB/4));
        const int4* C  = (const int4*)(p.vnb + (size_t)s1 * (DB/4));
        const int4* E  = (const int4*)(p.vnb + (size_t)d1 * (DB/4));
        int4 a0 = A[lane],  a1 = A[lane+64];
        int4 b0 = Bp[lane], b1 = Bp[lane+64];
        int4 c0 = C[lane],  c1 = C[lane+64];
        int4 e0 = E[lane],  e1 = E[lane+64];
        dot0 = fp8dot16(a0,b0) + fp8dot16(a1,b1);
        dot1 = fp8dot16(c0,e0) + fp8dot16(c1,e1);
    } else {
        const int s0 = p.esrc[i0], d0 = p.edst[i0], s1 = p.esrc[i0+1], d1 = p.edst[i0+1];
        const int2* A  = (const int2*)(p.vnf + (size_t)s0 * (DF/4));
        const int2* Bp = (const int2*)(p.vnf + (size_t)d0 * (DF/4));
        const int2* C  = (const int2*)(p.vnf + (size_t)s1 * (DF/4));
        const int2* E  = (const int2*)(p.vnf + (size_t)d1 * (DF/4));
        int2 a = A[lane], b = Bp[lane], c = C[lane], e = E[lane];
        dot0 = fp8dot4((unsigned)a.x,(unsigned)b.x) + fp8dot4((unsigned)a.y,(unsigned)b.y);
        dot1 = fp8dot4((unsigned)c.x,(unsigned)e.x) + fp8dot4((unsigned)c.y,(unsigned)e.y);
    }
    #pragma unroll
    for (int off = 1; off < 64; off <<= 1) {
        dot0 += __shfl_xor(dot0, off);
        dot1 += __shfl_xor(dot1, off);
    }
    if (lane == 0) ((float2*)p.w)[i0 >> 1] = make_float2(dot0, dot1);
}

// ===== L5: CSR gather + projections + final =====
__global__ __launch_bounds__(256) void gather_kernel(Params p) {
    const int wave = threadIdx.x >> 6, lane = threadIdx.x & 63;
    const int node = blockIdx.x * 4 + wave;
    const bool bodyhalf = lane < 32;
    const int c = lane & 31;
    const int sbase = bodyhalf ? 0 : (NN + 1);
    const int eofs = bodyhalf ? 0 : NE;
    const float* hl = bodyhalf ? p.hlb : p.hlf;
    const int s0 = p.starts[sbase + node], s1 = p.starts[sbase + node + 1];
    float acc = 0.f;
    for (int i = s0; i < s1; i++) {
        float wv = p.w[eofs + i];
        int s = p.esrc[eofs + i];
        acc += wv * hl[(size_t)s * HC + c];
    }
    float pr = acc * (bodyhalf ? p.pb_W : p.pf_W)[c];
    #pragma unroll
    for (int off = 16; off > 0; off >>= 1) pr += __shfl_down(pr, off);
    float tot = __shfl(pr, 0) + __shfl(pr, 32);
    if (lane == 0) p.out[node] = p.ns[node] + tot + p.pb_b[0] + p.pf_b[0];
}

extern "C" void kernel_launch(void* const* d_in, const int* in_sizes, int n_in,
                              void* d_out, int out_size, void* d_ws, size_t ws_size,
                              hipStream_t stream) {
    char* ws = (char*)d_ws;
    size_t off = 0;
    auto alloc = [&](size_t bytes) { void* pp = ws + off; off += (bytes + 15) & ~size_t(15); return pp; };

    Params p;
    p.vb      = (const float*)d_in[1];
    p.vf      = (const float*)d_in[2];
    p.x       = (const float*)d_in[0];
    p.Wq      = (const float*)d_in[3];
    p.Wk      = (const float*)d_in[4];
    p.Wv      = (const float*)d_in[5];
    p.ln_g    = (const float*)d_in[6];
    p.ln_b    = (const float*)d_in[7];
    p.prelu_a = (const float*)d_in[8];
    p.mlp_W   = (const float*)d_in[9];
    p.mlp_b   = (const float*)d_in[10];
    p.np_W    = (const float*)d_in[11];
    p.np_b    = (const float*)d_in[12];
    p.body_W  = (const float*)d_in[13];
    p.body_b  = (const float*)d_in[14];
    p.face_W  = (const float*)d_in[15];
    p.face_b  = (const float*)d_in[16];
    p.pb_W    = (const float*)d_in[17];
    p.pb_b    = (const float*)d_in[18];
    p.pf_W    = (const float*)d_in[19];
    p.pf_b    = (const float*)d_in[20];
    p.eib     = (const int*)d_in[21];
    p.eif     = (const int*)d_in[22];
    p.vnb     = (unsigned*)alloc((size_t)NN*(DB/4)*4);   // 16 MB fp8
    p.vnf     = (unsigned*)alloc((size_t)NN*(DF/4)*4);   //  4 MB fp8
    p.a_ws    = (float*)alloc((size_t)NN*2*4);
    p.ns      = (float*)alloc((size_t)NN*4);
    p.hlb     = (float*)alloc((size_t)NN*HC*4);
    p.hlf     = (float*)alloc((size_t)NN*HC*4);
    p.w       = (float*)alloc((size_t)2*NE*4);
    p.counts  = (int*)alloc((size_t)2*NN*4);
    p.starts  = (int*)alloc((size_t)2*(NN+1)*4);
    p.cursor  = (int*)alloc((size_t)2*NN*4);
    p.esrc    = (int*)alloc((size_t)2*NE*4);
    p.edst    = (int*)alloc((size_t)2*NE*4);
    p.out     = (float*)d_out;

    hipMemsetAsync(p.counts, 0, (size_t)2*NN*4, stream);
    fused1_kernel<<<NN/4 + NN/4 + (2*NE)/256 + NB, 256, 0, stream>>>(p);
    fused2_kernel<<<2 + NN/4, 256, 0, stream>>>(p);
    fill_kernel<<<(2*NE)/256, 256, 0, stream>>>(p);
    wdot_kernel<<<(2*NE)/8, 256, 0, stream>>>(p);
    gather_kernel<<<NN/4, 256, 0, stream>>>(p);
}

// Round 7
// 248.424 us; speedup vs baseline: 2.4432x; 1.0055x over previous
//
#include <hip/hip_runtime.h>

#define NN 8192     // nodes
#define NB 32       // graphs
#define NG 256      // nodes per graph
#define NE 65536    // edges per graph type
#define DK 512
#define HC 32
#define DB 2048     // body visual dim
#define DF 512      // face visual dim

typedef float v2f __attribute__((ext_vector_type(2)));

#if __has_builtin(__builtin_amdgcn_cvt_pk_f32_fp8) && __has_builtin(__builtin_amdgcn_cvt_pk_fp8_f32)
#define HW_FP8 1
#else
#define HW_FP8 0
#endif

// ---- fp8 e4m3fn helpers (manual fallback only if builtins missing) ----
__device__ __forceinline__ float fp8_dec(unsigned u) {
    unsigned e = (u >> 3) & 15u, m = u & 7u, s = u & 0x80u;
    float v = e ? __uint_as_float(((e + 120u) << 23) | (m << 20))
                : (float)m * 0.001953125f;
    return s ? -v : v;
}
__device__ __forceinline__ unsigned fp8_enc(float x) {
    unsigned sb = (__float_as_uint(x) >> 24) & 0x80u;
    float a = fabsf(x);
    if (a >= 448.f) return sb | 0x7Eu;
    if (a < 0.015625f) {
        int c = (int)rintf(a * 512.f);
        if (c > 7) return sb | 0x08u;
        return sb | (unsigned)c;
    }
    int ex; (void)frexpf(a, &ex);
    float p = ldexpf(a, 1 - ex);
    int m = (int)rintf((p - 1.f) * 8.f);
    int e = ex - 1 + 7;
    if (m == 8) { m = 0; e++; }
    if (e >= 16) return sb | 0x7Eu;
    return sb | (unsigned)(e << 3) | (unsigned)m;
}
__device__ __forceinline__ unsigned pack4_fp8(float x, float y, float z, float w) {
#if HW_FP8
    int u = __builtin_amdgcn_cvt_pk_fp8_f32(x, y, 0, false);
    u = __builtin_amdgcn_cvt_pk_fp8_f32(z, w, u, true);
    return (unsigned)u;
#else
    return fp8_enc(x) | (fp8_enc(y) << 8) | (fp8_enc(z) << 16) | (fp8_enc(w) << 24);
#endif
}
__device__ __forceinline__ float fp8dot4(unsigned a, unsigned b) {
#if HW_FP8
    v2f al = __builtin_amdgcn_cvt_pk_f32_fp8((int)a, false);
    v2f ah = __builtin_amdgcn_cvt_pk_f32_fp8((int)a, true);
    v2f bl = __builtin_amdgcn_cvt_pk_f32_fp8((int)b, false);
    v2f bh = __builtin_amdgcn_cvt_pk_f32_fp8((int)b, true);
    return al.x*bl.x + al.y*bl.y + ah.x*bh.x + ah.y*bh.y;
#else
    float s = 0.f;
    #pragma unroll
    for (int j = 0; j < 4; j++)
        s += fp8_dec((a >> (8*j)) & 255u) * fp8_dec((b >> (8*j)) & 255u);
    return s;
#endif
}
__device__ __forceinline__ float fp8dot16(int4 a, int4 b) {
    return fp8dot4((unsigned)a.x, (unsigned)b.x) + fp8dot4((unsigned)a.y, (unsigned)b.y)
         + fp8dot4((unsigned)a.z, (unsigned)b.z) + fp8dot4((unsigned)a.w, (unsigned)b.w);
}

struct Params {
    const float *vb, *vf, *x, *Wq, *Wk, *Wv, *ln_g, *ln_b, *prelu_a;
    const float *mlp_W, *mlp_b, *np_W, *np_b, *body_W, *body_b, *face_W, *face_b;
    const float *pb_W, *pb_b, *pf_W, *pf_b;
    const int *eib, *eif;
    unsigned *vnb, *vnf;
    float *a_ws, *ns, *hlb, *hlf, *w;
    int *counts, *starts, *cursor, *esrc, *edst;
    float *out;
};

// ===== L1: norm->fp8 (2 rows/wave, 16 loads in flight) + edge count + attention =====
// blocks [0, NN/8)            : body rows, 2 rows / wave
// blocks [NN/8, NN/4)         : face rows, 2 rows / wave
// blocks [NN/4, NN/4+512)     : degree count
// blocks [NN/4+512, +NB)      : rank-2 attention
__global__ __launch_bounds__(256) void fused1_kernel(Params p) {
    __shared__ float2 xs[NG];
    __shared__ float pm[4][4];
    __shared__ float sm4[4];
    const int bid = blockIdx.x, tid = threadIdx.x;
    const int lane = tid & 63, wave = tid >> 6;
    const int B_BODY = NN/8, B_FACE = NN/8, B_CNT = (2*NE)/256;

    if (bid < B_BODY) {
        const int node = bid * 8 + wave * 2;
        const float4* r0 = (const float4*)(p.vb + (size_t)node * DB);
        const float4* r1 = (const float4*)(p.vb + (size_t)(node + 1) * DB);
        float4 v0[8], v1[8];
        #pragma unroll
        for (int k = 0; k < 8; k++) v0[k] = r0[lane + 64*k];
        #pragma unroll
        for (int k = 0; k < 8; k++) v1[k] = r1[lane + 64*k];
        float s0 = 0.f, s1 = 0.f;
        #pragma unroll
        for (int k = 0; k < 8; k++) {
            s0 += v0[k].x*v0[k].x + v0[k].y*v0[k].y + v0[k].z*v0[k].z + v0[k].w*v0[k].w;
            s1 += v1[k].x*v1[k].x + v1[k].y*v1[k].y + v1[k].z*v1[k].z + v1[k].w*v1[k].w;
        }
        #pragma unroll
        for (int off = 1; off < 64; off <<= 1) {
            s0 += __shfl_xor(s0, off);
            s1 += __shfl_xor(s1, off);
        }
        const float i0 = rsqrtf(s0 + 1e-8f);
        const float i1 = rsqrtf(s1 + 1e-8f);
        unsigned* o0 = p.vnb + (size_t)node * (DB/4);
        unsigned* o1 = p.vnb + (size_t)(node + 1) * (DB/4);
        #pragma unroll
        for (int k = 0; k < 8; k++)
            o0[lane + 64*k] = pack4_fp8(v0[k].x*i0, v0[k].y*i0, v0[k].z*i0, v0[k].w*i0);
        #pragma unroll
        for (int k = 0; k < 8; k++)
            o1[lane + 64*k] = pack4_fp8(v1[k].x*i1, v1[k].y*i1, v1[k].z*i1, v1[k].w*i1);
    } else if (bid < B_BODY + B_FACE) {
        const int node = (bid - B_BODY) * 8 + wave * 2;
        const float4* r0 = (const float4*)(p.vf + (size_t)node * DF);
        const float4* r1 = (const float4*)(p.vf + (size_t)(node + 1) * DF);
        float4 a0 = r0[lane], a1 = r0[lane + 64];
        float4 b0 = r1[lane], b1 = r1[lane + 64];
        float s0 = a0.x*a0.x + a0.y*a0.y + a0.z*a0.z + a0.w*a0.w
                 + a1.x*a1.x + a1.y*a1.y + a1.z*a1.z + a1.w*a1.w;
        float s1 = b0.x*b0.x + b0.y*b0.y + b0.z*b0.z + b0.w*b0.w
                 + b1.x*b1.x + b1.y*b1.y + b1.z*b1.z + b1.w*b1.w;
        #pragma unroll
        for (int off = 1; off < 64; off <<= 1) {
            s0 += __shfl_xor(s0, off);
            s1 += __shfl_xor(s1, off);
        }
        const float i0 = rsqrtf(s0 + 1e-8f);
        const float i1 = rsqrtf(s1 + 1e-8f);
        unsigned* o0 = p.vnf + (size_t)node * (DF/4);
        unsigned* o1 = p.vnf + (size_t)(node + 1) * (DF/4);
        o0[lane]      = pack4_fp8(a0.x*i0, a0.y*i0, a0.z*i0, a0.w*i0);
        o0[lane + 64] = pack4_fp8(a1.x*i0, a1.y*i0, a1.z*i0, a1.w*i0);
        o1[lane]      = pack4_fp8(b0.x*i1, b0.y*i1, b0.z*i1, b0.w*i1);
        o1[lane + 64] = pack4_fp8(b1.x*i1, b1.y*i1, b1.z*i1, b1.w*i1);
    } else if (bid < B_BODY + B_FACE + B_CNT) {
        const int e = (bid - B_BODY - B_FACE) * 256 + tid;
        if (e < NE) atomicAdd(&p.counts[p.eib[NE + e]], 1);
        else        atomicAdd(&p.counts[NN + p.eif[NE + (e - NE)]], 1);
    } else {
        const int gg = bid - (B_BODY + B_FACE + B_CNT);
        xs[tid] = ((const float2*)p.x)[gg*NG + tid];
        const int d = tid * 2;
        float q0a = p.Wq[d],    q0b = p.Wq[d+1];
        float q1a = p.Wq[DK+d], q1b = p.Wq[DK+d+1];
        float k0a = p.Wk[d],    k0b = p.Wk[d+1];
        float k1a = p.Wk[DK+d], k1b = p.Wk[DK+d+1];
        float m00 = q0a*k0a + q0b*k0b;
        float m01 = q0a*k1a + q0b*k1b;
        float m10 = q1a*k0a + q1b*k0b;
        float m11 = q1a*k1a + q1b*k1b;
        #pragma unroll
        for (int off = 32; off > 0; off >>= 1) {
            m00 += __shfl_down(m00,off); m01 += __shfl_down(m01,off);
            m10 += __shfl_down(m10,off); m11 += __shfl_down(m11,off);
        }
        if (lane == 0) { pm[wave][0]=m00; pm[wave][1]=m01; pm[wave][2]=m10; pm[wave][3]=m11; }
        __syncthreads();
        if (tid < 4) sm4[tid] = pm[0][tid] + pm[1][tid] + pm[2][tid] + pm[3][tid];
        __syncthreads();
        const float scale = 0.04419417382415922f;  // 1/sqrt(512)
        const float2 xi = xs[tid];
        const float u0 = (xi.x*sm4[0] + xi.y*sm4[2]) * scale;
        const float u1 = (xi.x*sm4[1] + xi.y*sm4[3]) * scale;
        float m = -1e30f;
        for (int j = 0; j < NG; j++) m = fmaxf(m, u0*xs[j].x + u1*xs[j].y);
        float S = 0.f, a0 = 0.f, a1 = 0.f;
        for (int j = 0; j < NG; j++) {
            float2 xj = xs[j];
            float pr = __expf(u0*xj.x + u1*xj.y - m);
            S += pr; a0 += pr*xj.x; a1 += pr*xj.y;
        }
        const float invS = 1.f / S;
        ((float2*)p.a_ws)[gg*NG + tid] = make_float2(a0*invS, a1*invS);
    }
}

// ===== L2: CSR scan (blocks 0,1) + per-node MLP pipeline =====
__global__ __launch_bounds__(256) void fused2_kernel(Params p) {
    __shared__ int part[256];
    __shared__ float t[4][DK];
    __shared__ float hbuf[4][HC];
    const int bid = blockIdx.x, tid = threadIdx.x;
    if (bid < 2) {
        const int cbase = bid * NN;
        const int sbase = bid * (NN + 1);
        int loc[32];
        int sum = 0;
        #pragma unroll
        for (int j = 0; j < 32; j++) { loc[j] = p.counts[cbase + tid*32 + j]; sum += loc[j]; }
        part[tid] = sum;
        __syncthreads();
        for (int off = 1; off < 256; off <<= 1) {
            int v = (tid >= off) ? part[tid - off] : 0;
            __syncthreads();
            part[tid] += v;
            __syncthreads();
        }
        int run = (tid == 0) ? 0 : part[tid - 1];
        #pragma unroll
        for (int j = 0; j < 32; j++) {
            p.starts[sbase + tid*32 + j] = run;
            p.cursor[cbase + tid*32 + j] = run;
            run += loc[j];
        }
        if (tid == 255) p.starts[sbase + NN] = run;
        return;
    }
    const int wave = tid >> 6, lane = tid & 63;
    const int node = (bid - 2) * 4 + wave;
    const float a0 = p.a_ws[node*2], a1 = p.a_ws[node*2+1];
    const float4* wv0 = (const float4*)p.Wv;
    const float4* wv1 = (const float4*)(p.Wv + DK);
    const float4* g4 = (const float4*)p.ln_g;
    const float4* b4 = (const float4*)p.ln_b;
    float4 W0[2], W1[2], Gg[2], Bb[2];
    #pragma unroll
    for (int k = 0; k < 2; k++) {
        int c4 = lane*2 + k;
        W0[k] = wv0[c4]; W1[k] = wv1[c4]; Gg[k] = g4[c4]; Bb[k] = b4[c4];
    }
    float s0=0.f, s1=0.f, q00=0.f, q01=0.f, q11=0.f;
    #pragma unroll
    for (int k = 0; k < 2; k++) {
        const float* u = (const float*)&W0[k];
        const float* v = (const float*)&W1[k];
        #pragma unroll
        for (int j = 0; j < 4; j++) {
            s0 += u[j]; s1 += v[j];
            q00 += u[j]*u[j]; q01 += u[j]*v[j]; q11 += v[j]*v[j];
        }
    }
    #pragma unroll
    for (int off = 1; off < 64; off <<= 1) {
        s0 += __shfl_xor(s0,off); s1 += __shfl_xor(s1,off);
        q00 += __shfl_xor(q00,off); q01 += __shfl_xor(q01,off); q11 += __shfl_xor(q11,off);
    }
    const float mean = (a0*s0 + a1*s1) * (1.f/DK);
    const float msq  = (a0*a0*q00 + 2.f*a0*a1*q01 + a1*a1*q11) * (1.f/DK);
    const float inv  = rsqrtf(msq - mean*mean + 1e-5f);
    const float alpha = p.prelu_a[0];
    #pragma unroll
    for (int k = 0; k < 2; k++) {
        int c4 = lane*2 + k;
        const float* u = (const float*)&W0[k];
        const float* v = (const float*)&W1[k];
        const float* gf = (const float*)&Gg[k];
        const float* bf = (const float*)&Bb[k];
        #pragma unroll
        for (int j = 0; j < 4; j++) {
            float od = a0*u[j] + a1*v[j];
            float nd = (od - mean) * inv * gf[j] + bf[j];
            t[wave][c4*4 + j] = (nd >= 0.f) ? nd : alpha*nd;
        }
    }
    __syncthreads();
    const int c = lane & 31, half = lane >> 5;
    const float* tp = t[wave] + half*256;
    const float* mw = p.mlp_W + half*256*HC + c;
    float partl = 0.f;
    for (int d = 0; d < 256; d++) partl += tp[d] * mw[d*HC];
    partl += __shfl_down(partl, 32);
    float hc = 0.f;
    if (lane < 32) { hc = partl + p.mlp_b[c]; hbuf[wave][c] = hc; }
    __syncthreads();
    float sp = (lane < 32) ? hc * p.np_W[c] : 0.f;
    #pragma unroll
    for (int off = 16; off > 0; off >>= 1) sp += __shfl_down(sp, off);
    if (lane == 0) p.ns[node] = sp + p.np_b[0];
    const float* hb_ = hbuf[wave];
    if (lane < 32) {
        float acc2 = p.body_b[c];
        #pragma unroll 8
        for (int cp = 0; cp < HC; cp++) acc2 += hb_[cp] * p.body_W[cp*HC + c];
        p.hlb[(size_t)node*HC + c] = acc2;
    } else {
        float acc2 = p.face_b[c];
        #pragma unroll 8
        for (int cp = 0; cp < HC; cp++) acc2 += hb_[cp] * p.face_W[cp*HC + c];
        p.hlf[(size_t)node*HC + c] = acc2;
    }
}

// ===== L3: CSR fill =====
__global__ __launch_bounds__(256) void fill_kernel(Params p) {
    const int e = blockIdx.x * 256 + threadIdx.x;
    if (e < NE) {
        int s = p.eib[e], d = p.eib[NE + e];
        int pos = atomicAdd(&p.cursor[d], 1);
        p.esrc[pos] = s; p.edst[pos] = d;
    } else {
        int e2 = e - NE;
        int s = p.eif[e2], d = p.eif[NE + e2];
        int pos = atomicAdd(&p.cursor[NN + d], 1);
        p.esrc[NE + pos] = s; p.edst[NE + pos] = d;
    }
}

// ===== L4: edge cosines in CSR order (4 edges / wave, 16 loads in flight) =====
// blocks [0, NE/16)        : body edges
// blocks [NE/16, 2*NE/16)  : face edges
__global__ __launch_bounds__(256) void wdot_kernel(Params p) {
    const int wave = threadIdx.x >> 6, lane = threadIdx.x & 63;
    const int BB = NE/16;
    float d0, d1, d2, d3;
    int i0;
    if (blockIdx.x < BB) {
        i0 = (blockIdx.x * 4 + wave) * 4;
        const int s0 = p.esrc[i0],   sd0 = p.edst[i0];
        const int s1 = p.esrc[i0+1], sd1 = p.edst[i0+1];
        const int s2 = p.esrc[i0+2], sd2 = p.edst[i0+2];
        const int s3 = p.esrc[i0+3], sd3 = p.edst[i0+3];
        const int4* A0 = (const int4*)(p.vnb + (size_t)s0  * (DB/4));
        const int4* B0 = (const int4*)(p.vnb + (size_t)sd0 * (DB/4));
        const int4* A1 = (const int4*)(p.vnb + (size_t)s1  * (DB/4));
        const int4* B1 = (const int4*)(p.vnb + (size_t)sd1 * (DB/4));
        const int4* A2 = (const int4*)(p.vnb + (size_t)s2  * (DB/4));
        const int4* B2 = (const int4*)(p.vnb + (size_t)sd2 * (DB/4));
        const int4* A3 = (const int4*)(p.vnb + (size_t)s3  * (DB/4));
        const int4* B3 = (const int4*)(p.vnb + (size_t)sd3 * (DB/4));
        int4 a00 = A0[lane], a01 = A0[lane+64];
        int4 b00 = B0[lane], b01 = B0[lane+64];
        int4 a10 = A1[lane], a11 = A1[lane+64];
        int4 b10 = B1[lane], b11 = B1[lane+64];
        int4 a20 = A2[lane], a21 = A2[lane+64];
        int4 b20 = B2[lane], b21 = B2[lane+64];
        int4 a30 = A3[lane], a31 = A3[lane+64];
        int4 b30 = B3[lane], b31 = B3[lane+64];
        d0 = fp8dot16(a00,b00) + fp8dot16(a01,b01);
        d1 = fp8dot16(a10,b10) + fp8dot16(a11,b11);
        d2 = fp8dot16(a20,b20) + fp8dot16(a21,b21);
        d3 = fp8dot16(a30,b30) + fp8dot16(a31,b31);
    } else {
        i0 = NE + ((blockIdx.x - BB) * 4 + wave) * 4;
        const int s0 = p.esrc[i0],   sd0 = p.edst[i0];
        const int s1 = p.esrc[i0+1], sd1 = p.edst[i0+1];
        const int s2 = p.esrc[i0+2], sd2 = p.edst[i0+2];
        const int s3 = p.esrc[i0+3], sd3 = p.edst[i0+3];
        const int2* A0 = (const int2*)(p.vnf + (size_t)s0  * (DF/4));
        const int2* B0 = (const int2*)(p.vnf + (size_t)sd0 * (DF/4));
        const int2* A1 = (const int2*)(p.vnf + (size_t)s1  * (DF/4));
        const int2* B1 = (const int2*)(p.vnf + (size_t)sd1 * (DF/4));
        const int2* A2 = (const int2*)(p.vnf + (size_t)s2  * (DF/4));
        const int2* B2 = (const int2*)(p.vnf + (size_t)sd2 * (DF/4));
        const int2* A3 = (const int2*)(p.vnf + (size_t)s3  * (DF/4));
        const int2* B3 = (const int2*)(p.vnf + (size_t)sd3 * (DF/4));
        int2 a0 = A0[lane], b0 = B0[lane];
        int2 a1 = A1[lane], b1 = B1[lane];
        int2 a2 = A2[lane], b2 = B2[lane];
        int2 a3 = A3[lane], b3 = B3[lane];
        d0 = fp8dot4((unsigned)a0.x,(unsigned)b0.x) + fp8dot4((unsigned)a0.y,(unsigned)b0.y);
        d1 = fp8dot4((unsigned)a1.x,(unsigned)b1.x) + fp8dot4((unsigned)a1.y,(unsigned)b1.y);
        d2 = fp8dot4((unsigned)a2.x,(unsigned)b2.x) + fp8dot4((unsigned)a2.y,(unsigned)b2.y);
        d3 = fp8dot4((unsigned)a3.x,(unsigned)b3.x) + fp8dot4((unsigned)a3.y,(unsigned)b3.y);
    }
    #pragma unroll
    for (int off = 1; off < 64; off <<= 1) {
        d0 += __shfl_xor(d0, off);
        d1 += __shfl_xor(d1, off);
        d2 += __shfl_xor(d2, off);
        d3 += __shfl_xor(d3, off);
    }
    if (lane == 0) ((float4*)p.w)[i0 >> 2] = make_float4(d0, d1, d2, d3);
}

// ===== L5: CSR gather + projections + final =====
__global__ __launch_bounds__(256) void gather_kernel(Params p) {
    const int wave = threadIdx.x >> 6, lane = threadIdx.x & 63;
    const int node = blockIdx.x * 4 + wave;
    const bool bodyhalf = lane < 32;
    const int c = lane & 31;
    const int sbase = bodyhalf ? 0 : (NN + 1);
    const int eofs = bodyhalf ? 0 : NE;
    const float* hl = bodyhalf ? p.hlb : p.hlf;
    const int s0 = p.starts[sbase + node], s1 = p.starts[sbase + node + 1];
    float acc = 0.f;
    for (int i = s0; i < s1; i++) {
        float wv = p.w[eofs + i];
        int s = p.esrc[eofs + i];
        acc += wv * hl[(size_t)s * HC + c];
    }
    float pr = acc * (bodyhalf ? p.pb_W : p.pf_W)[c];
    #pragma unroll
    for (int off = 16; off > 0; off >>= 1) pr += __shfl_down(pr, off);
    float tot = __shfl(pr, 0) + __shfl(pr, 32);
    if (lane == 0) p.out[node] = p.ns[node] + tot + p.pb_b[0] + p.pf_b[0];
}

extern "C" void kernel_launch(void* const* d_in, const int* in_sizes, int n_in,
                              void* d_out, int out_size, void* d_ws, size_t ws_size,
                              hipStream_t stream) {
    char* ws = (char*)d_ws;
    size_t off = 0;
    auto alloc = [&](size_t bytes) { void* pp = ws + off; off += (bytes + 15) & ~size_t(15); return pp; };

    Params p;
    p.vb      = (const float*)d_in[1];
    p.vf      = (const float*)d_in[2];
    p.x       = (const float*)d_in[0];
    p.Wq      = (const float*)d_in[3];
    p.Wk      = (const float*)d_in[4];
    p.Wv      = (const float*)d_in[5];
    p.ln_g    = (const float*)d_in[6];
    p.ln_b    = (const float*)d_in[7];
    p.prelu_a = (const float*)d_in[8];
    p.mlp_W   = (const float*)d_in[9];
    p.mlp_b   = (const float*)d_in[10];
    p.np_W    = (const float*)d_in[11];
    p.np_b    = (const float*)d_in[12];
    p.body_W  = (const float*)d_in[13];
    p.body_b  = (const float*)d_in[14];
    p.face_W  = (const float*)d_in[15];
    p.face_b  = (const float*)d_in[16];
    p.pb_W    = (const float*)d_in[17];
    p.pb_b    = (const float*)d_in[18];
    p.pf_W    = (const float*)d_in[19];
    p.pf_b    = (const float*)d_in[20];
    p.eib     = (const int*)d_in[21];
    p.eif     = (const int*)d_in[22];
    p.vnb     = (unsigned*)alloc((size_t)NN*(DB/4)*4);   // 16 MB fp8
    p.vnf     = (unsigned*)alloc((size_t)NN*(DF/4)*4);   //  4 MB fp8
    p.a_ws    = (float*)alloc((size_t)NN*2*4);
    p.ns      = (float*)alloc((size_t)NN*4);
    p.hlb     = (float*)alloc((size_t)NN*HC*4);
    p.hlf     = (float*)alloc((size_t)NN*HC*4);
    p.w       = (float*)alloc((size_t)2*NE*4);
    p.counts  = (int*)alloc((size_t)2*NN*4);
    p.starts  = (int*)alloc((size_t)2*(NN+1)*4);
    p.cursor  = (int*)alloc((size_t)2*NN*4);
    p.esrc    = (int*)alloc((size_t)2*NE*4);
    p.edst    = (int*)alloc((size_t)2*NE*4);
    p.out     = (float*)d_out;

    hipMemsetAsync(p.counts, 0, (size_t)2*NN*4, stream);
    fused1_kernel<<<NN/8 + NN/8 + (2*NE)/256 + NB, 256, 0, stream>>>(p);
    fused2_kernel<<<2 + NN/4, 256, 0, stream>>>(p);
    fill_kernel<<<(2*NE)/256, 256, 0, stream>>>(p);
    wdot_kernel<<<2*(NE/16), 256, 0, stream>>>(p);
    gather_kernel<<<NN/4, 256, 0, stream>>>(p);
}

// Round 8
// 247.427 us; speedup vs baseline: 2.4531x; 1.0040x over previous
//
#include <hip/hip_runtime.h>

#define NN 8192     // nodes
#define NB 32       // graphs
#define NG 256      // nodes per graph
#define NE 65536    // edges per graph type
#define DK 512
#define HC 32
#define DB 2048     // body visual dim
#define DF 512      // face visual dim

typedef float v2f __attribute__((ext_vector_type(2)));

#if __has_builtin(__builtin_amdgcn_cvt_pk_f32_fp8) && __has_builtin(__builtin_amdgcn_cvt_pk_fp8_f32)
#define HW_FP8 1
#else
#define HW_FP8 0
#endif

// ---- fp8 e4m3fn helpers (manual fallback only if builtins missing) ----
__device__ __forceinline__ float fp8_dec(unsigned u) {
    unsigned e = (u >> 3) & 15u, m = u & 7u, s = u & 0x80u;
    float v = e ? __uint_as_float(((e + 120u) << 23) | (m << 20))
                : (float)m * 0.001953125f;
    return s ? -v : v;
}
__device__ __forceinline__ unsigned fp8_enc(float x) {
    unsigned sb = (__float_as_uint(x) >> 24) & 0x80u;
    float a = fabsf(x);
    if (a >= 448.f) return sb | 0x7Eu;
    if (a < 0.015625f) {
        int c = (int)rintf(a * 512.f);
        if (c > 7) return sb | 0x08u;
        return sb | (unsigned)c;
    }
    int ex; (void)frexpf(a, &ex);
    float p = ldexpf(a, 1 - ex);
    int m = (int)rintf((p - 1.f) * 8.f);
    int e = ex - 1 + 7;
    if (m == 8) { m = 0; e++; }
    if (e >= 16) return sb | 0x7Eu;
    return sb | (unsigned)(e << 3) | (unsigned)m;
}
__device__ __forceinline__ unsigned pack4_fp8(float x, float y, float z, float w) {
#if HW_FP8
    int u = __builtin_amdgcn_cvt_pk_fp8_f32(x, y, 0, false);
    u = __builtin_amdgcn_cvt_pk_fp8_f32(z, w, u, true);
    return (unsigned)u;
#else
    return fp8_enc(x) | (fp8_enc(y) << 8) | (fp8_enc(z) << 16) | (fp8_enc(w) << 24);
#endif
}
__device__ __forceinline__ float fp8dot4(unsigned a, unsigned b) {
#if HW_FP8
    v2f al = __builtin_amdgcn_cvt_pk_f32_fp8((int)a, false);
    v2f ah = __builtin_amdgcn_cvt_pk_f32_fp8((int)a, true);
    v2f bl = __builtin_amdgcn_cvt_pk_f32_fp8((int)b, false);
    v2f bh = __builtin_amdgcn_cvt_pk_f32_fp8((int)b, true);
    return al.x*bl.x + al.y*bl.y + ah.x*bh.x + ah.y*bh.y;
#else
    float s = 0.f;
    #pragma unroll
    for (int j = 0; j < 4; j++)
        s += fp8_dec((a >> (8*j)) & 255u) * fp8_dec((b >> (8*j)) & 255u);
    return s;
#endif
}
__device__ __forceinline__ float fp8dot16(int4 a, int4 b) {
    return fp8dot4((unsigned)a.x, (unsigned)b.x) + fp8dot4((unsigned)a.y, (unsigned)b.y)
         + fp8dot4((unsigned)a.z, (unsigned)b.z) + fp8dot4((unsigned)a.w, (unsigned)b.w);
}

struct Params {
    const float *vb, *vf, *x, *Wq, *Wk, *Wv, *ln_g, *ln_b, *prelu_a;
    const float *mlp_W, *mlp_b, *np_W, *np_b, *body_W, *body_b, *face_W, *face_b;
    const float *pb_W, *pb_b, *pf_W, *pf_b;
    const int *eib, *eif;
    unsigned *vnb, *vnf;
    float *invb, *invf;
    float *a_ws, *ns, *hlb, *hlf, *w;
    int *counts, *starts, *cursor, *esrc, *edst;
    float *out;
};

// ===== L1: raw fp8 pack + row invnorm (single pass, dependency-free stores)
//          + edge count + attention =====
// blocks [0, NN/4)            : body rows, 1 row / wave
// blocks [NN/4, NN/2)         : face rows, 1 row / wave
// blocks [NN/2, NN/2+512)     : degree count
// blocks [NN/2+512, +NB)      : rank-2 attention
__global__ __launch_bounds__(256) void fused1_kernel(Params p) {
    __shared__ float2 xs[NG];
    __shared__ float pm[4][4];
    __shared__ float sm4[4];
    const int bid = blockIdx.x, tid = threadIdx.x;
    const int lane = tid & 63, wave = tid >> 6;
    const int B_BODY = NN/4, B_FACE = NN/4, B_CNT = (2*NE)/256;

    if (bid < B_BODY) {
        const int node = bid * 4 + wave;
        const float4* r4 = (const float4*)(p.vb + (size_t)node * DB);
        unsigned* orow = p.vnb + (size_t)node * (DB/4);
        float ss = 0.f;
        #pragma unroll
        for (int k = 0; k < 8; k++) {
            float4 v = r4[lane + 64*k];
            orow[lane + 64*k] = pack4_fp8(v.x, v.y, v.z, v.w);
            ss += v.x*v.x + v.y*v.y + v.z*v.z + v.w*v.w;
        }
        #pragma unroll
        for (int off = 1; off < 64; off <<= 1) ss += __shfl_xor(ss, off);
        if (lane == 0) p.invb[node] = rsqrtf(ss + 1e-8f);
    } else if (bid < B_BODY + B_FACE) {
        const int node = (bid - B_BODY) * 4 + wave;
        const float4* r4 = (const float4*)(p.vf + (size_t)node * DF);
        unsigned* orow = p.vnf + (size_t)node * (DF/4);
        float4 a = r4[lane], b = r4[lane + 64];
        orow[lane]      = pack4_fp8(a.x, a.y, a.z, a.w);
        orow[lane + 64] = pack4_fp8(b.x, b.y, b.z, b.w);
        float ss = a.x*a.x + a.y*a.y + a.z*a.z + a.w*a.w
                 + b.x*b.x + b.y*b.y + b.z*b.z + b.w*b.w;
        #pragma unroll
        for (int off = 1; off < 64; off <<= 1) ss += __shfl_xor(ss, off);
        if (lane == 0) p.invf[node] = rsqrtf(ss + 1e-8f);
    } else if (bid < B_BODY + B_FACE + B_CNT) {
        const int e = (bid - B_BODY - B_FACE) * 256 + tid;
        if (e < NE) atomicAdd(&p.counts[p.eib[NE + e]], 1);
        else        atomicAdd(&p.counts[NN + p.eif[NE + (e - NE)]], 1);
    } else {
        const int gg = bid - (B_BODY + B_FACE + B_CNT);
        xs[tid] = ((const float2*)p.x)[gg*NG + tid];
        const int d = tid * 2;
        float q0a = p.Wq[d],    q0b = p.Wq[d+1];
        float q1a = p.Wq[DK+d], q1b = p.Wq[DK+d+1];
        float k0a = p.Wk[d],    k0b = p.Wk[d+1];
        float k1a = p.Wk[DK+d], k1b = p.Wk[DK+d+1];
        float m00 = q0a*k0a + q0b*k0b;
        float m01 = q0a*k1a + q0b*k1b;
        float m10 = q1a*k0a + q1b*k0b;
        float m11 = q1a*k1a + q1b*k1b;
        #pragma unroll
        for (int off = 32; off > 0; off >>= 1) {
            m00 += __shfl_down(m00,off); m01 += __shfl_down(m01,off);
            m10 += __shfl_down(m10,off); m11 += __shfl_down(m11,off);
        }
        if (lane == 0) { pm[wave][0]=m00; pm[wave][1]=m01; pm[wave][2]=m10; pm[wave][3]=m11; }
        __syncthreads();
        if (tid < 4) sm4[tid] = pm[0][tid] + pm[1][tid] + pm[2][tid] + pm[3][tid];
        __syncthreads();
        const float scale = 0.04419417382415922f;  // 1/sqrt(512)
        const float2 xi = xs[tid];
        const float u0 = (xi.x*sm4[0] + xi.y*sm4[2]) * scale;
        const float u1 = (xi.x*sm4[1] + xi.y*sm4[3]) * scale;
        float m = -1e30f;
        for (int j = 0; j < NG; j++) m = fmaxf(m, u0*xs[j].x + u1*xs[j].y);
        float S = 0.f, a0 = 0.f, a1 = 0.f;
        for (int j = 0; j < NG; j++) {
            float2 xj = xs[j];
            float pr = __expf(u0*xj.x + u1*xj.y - m);
            S += pr; a0 += pr*xj.x; a1 += pr*xj.y;
        }
        const float invS = 1.f / S;
        ((float2*)p.a_ws)[gg*NG + tid] = make_float2(a0*invS, a1*invS);
    }
}

// ===== L2: CSR scan (blocks 0,1) + per-node MLP pipeline =====
__global__ __launch_bounds__(256) void fused2_kernel(Params p) {
    __shared__ int part[256];
    __shared__ float t[4][DK];
    __shared__ float hbuf[4][HC];
    const int bid = blockIdx.x, tid = threadIdx.x;
    if (bid < 2) {
        const int cbase = bid * NN;
        const int sbase = bid * (NN + 1);
        int loc[32];
        int sum = 0;
        #pragma unroll
        for (int j = 0; j < 32; j++) { loc[j] = p.counts[cbase + tid*32 + j]; sum += loc[j]; }
        part[tid] = sum;
        __syncthreads();
        for (int off = 1; off < 256; off <<= 1) {
            int v = (tid >= off) ? part[tid - off] : 0;
            __syncthreads();
            part[tid] += v;
            __syncthreads();
        }
        int run = (tid == 0) ? 0 : part[tid - 1];
        #pragma unroll
        for (int j = 0; j < 32; j++) {
            p.starts[sbase + tid*32 + j] = run;
            p.cursor[cbase + tid*32 + j] = run;
            run += loc[j];
        }
        if (tid == 255) p.starts[sbase + NN] = run;
        return;
    }
    const int wave = tid >> 6, lane = tid & 63;
    const int node = (bid - 2) * 4 + wave;
    const float a0 = p.a_ws[node*2], a1 = p.a_ws[node*2+1];
    const float4* wv0 = (const float4*)p.Wv;
    const float4* wv1 = (const float4*)(p.Wv + DK);
    const float4* g4 = (const float4*)p.ln_g;
    const float4* b4 = (const float4*)p.ln_b;
    float4 W0[2], W1[2], Gg[2], Bb[2];
    #pragma unroll
    for (int k = 0; k < 2; k++) {
        int c4 = lane*2 + k;
        W0[k] = wv0[c4]; W1[k] = wv1[c4]; Gg[k] = g4[c4]; Bb[k] = b4[c4];
    }
    float s0=0.f, s1=0.f, q00=0.f, q01=0.f, q11=0.f;
    #pragma unroll
    for (int k = 0; k < 2; k++) {
        const float* u = (const float*)&W0[k];
        const float* v = (const float*)&W1[k];
        #pragma unroll
        for (int j = 0; j < 4; j++) {
            s0 += u[j]; s1 += v[j];
            q00 += u[j]*u[j]; q01 += u[j]*v[j]; q11 += v[j]*v[j];
        }
    }
    #pragma unroll
    for (int off = 1; off < 64; off <<= 1) {
        s0 += __shfl_xor(s0,off); s1 += __shfl_xor(s1,off);
        q00 += __shfl_xor(q00,off); q01 += __shfl_xor(q01,off); q11 += __shfl_xor(q11,off);
    }
    const float mean = (a0*s0 + a1*s1) * (1.f/DK);
    const float msq  = (a0*a0*q00 + 2.f*a0*a1*q01 + a1*a1*q11) * (1.f/DK);
    const float inv  = rsqrtf(msq - mean*mean + 1e-5f);
    const float alpha = p.prelu_a[0];
    #pragma unroll
    for (int k = 0; k < 2; k++) {
        int c4 = lane*2 + k;
        const float* u = (const float*)&W0[k];
        const float* v = (const float*)&W1[k];
        const float* gf = (const float*)&Gg[k];
        const float* bf = (const float*)&Bb[k];
        #pragma unroll
        for (int j = 0; j < 4; j++) {
            float od = a0*u[j] + a1*v[j];
            float nd = (od - mean) * inv * gf[j] + bf[j];
            t[wave][c4*4 + j] = (nd >= 0.f) ? nd : alpha*nd;
        }
    }
    __syncthreads();
    const int c = lane & 31, half = lane >> 5;
    const float* tp = t[wave] + half*256;
    const float* mw = p.mlp_W + half*256*HC + c;
    float partl = 0.f;
    for (int d = 0; d < 256; d++) partl += tp[d] * mw[d*HC];
    partl += __shfl_down(partl, 32);
    float hc = 0.f;
    if (lane < 32) { hc = partl + p.mlp_b[c]; hbuf[wave][c] = hc; }
    __syncthreads();
    float sp = (lane < 32) ? hc * p.np_W[c] : 0.f;
    #pragma unroll
    for (int off = 16; off > 0; off >>= 1) sp += __shfl_down(sp, off);
    if (lane == 0) p.ns[node] = sp + p.np_b[0];
    const float* hb_ = hbuf[wave];
    if (lane < 32) {
        float acc2 = p.body_b[c];
        #pragma unroll 8
        for (int cp = 0; cp < HC; cp++) acc2 += hb_[cp] * p.body_W[cp*HC + c];
        p.hlb[(size_t)node*HC + c] = acc2;
    } else {
        float acc2 = p.face_b[c];
        #pragma unroll 8
        for (int cp = 0; cp < HC; cp++) acc2 += hb_[cp] * p.face_W[cp*HC + c];
        p.hlf[(size_t)node*HC + c] = acc2;
    }
}

// ===== L3: CSR fill =====
__global__ __launch_bounds__(256) void fill_kernel(Params p) {
    const int e = blockIdx.x * 256 + threadIdx.x;
    if (e < NE) {
        int s = p.eib[e], d = p.eib[NE + e];
        int pos = atomicAdd(&p.cursor[d], 1);
        p.esrc[pos] = s; p.edst[pos] = d;
    } else {
        int e2 = e - NE;
        int s = p.eif[e2], d = p.eif[NE + e2];
        int pos = atomicAdd(&p.cursor[NN + d], 1);
        p.esrc[NE + pos] = s; p.edst[NE + pos] = d;
    }
}

// ===== L4: edge cosines in CSR order (4 edges / wave) =====
// cos = rawdot * invn[src] * invn[dst]
__global__ __launch_bounds__(256) void wdot_kernel(Params p) {
    const int wave = threadIdx.x >> 6, lane = threadIdx.x & 63;
    const int BB = NE/16;
    float d0, d1, d2, d3;
    int i0;
    int s0, s1, s2, s3, t0, t1, t2, t3;
    const float* invp;
    if (blockIdx.x < BB) {
        i0 = (blockIdx.x * 4 + wave) * 4;
        invp = p.invb;
        s0 = p.esrc[i0];   t0 = p.edst[i0];
        s1 = p.esrc[i0+1]; t1 = p.edst[i0+1];
        s2 = p.esrc[i0+2]; t2 = p.edst[i0+2];
        s3 = p.esrc[i0+3]; t3 = p.edst[i0+3];
        const int4* A0 = (const int4*)(p.vnb + (size_t)s0 * (DB/4));
        const int4* B0 = (const int4*)(p.vnb + (size_t)t0 * (DB/4));
        const int4* A1 = (const int4*)(p.vnb + (size_t)s1 * (DB/4));
        const int4* B1 = (const int4*)(p.vnb + (size_t)t1 * (DB/4));
        const int4* A2 = (const int4*)(p.vnb + (size_t)s2 * (DB/4));
        const int4* B2 = (const int4*)(p.vnb + (size_t)t2 * (DB/4));
        const int4* A3 = (const int4*)(p.vnb + (size_t)s3 * (DB/4));
        const int4* B3 = (const int4*)(p.vnb + (size_t)t3 * (DB/4));
        int4 a00 = A0[lane], a01 = A0[lane+64];
        int4 b00 = B0[lane], b01 = B0[lane+64];
        int4 a10 = A1[lane], a11 = A1[lane+64];
        int4 b10 = B1[lane], b11 = B1[lane+64];
        int4 a20 = A2[lane], a21 = A2[lane+64];
        int4 b20 = B2[lane], b21 = B2[lane+64];
        int4 a30 = A3[lane], a31 = A3[lane+64];
        int4 b30 = B3[lane], b31 = B3[lane+64];
        d0 = fp8dot16(a00,b00) + fp8dot16(a01,b01);
        d1 = fp8dot16(a10,b10) + fp8dot16(a11,b11);
        d2 = fp8dot16(a20,b20) + fp8dot16(a21,b21);
        d3 = fp8dot16(a30,b30) + fp8dot16(a31,b31);
    } else {
        i0 = NE + ((blockIdx.x - BB) * 4 + wave) * 4;
        invp = p.invf;
        s0 = p.esrc[i0];   t0 = p.edst[i0];
        s1 = p.esrc[i0+1]; t1 = p.edst[i0+1];
        s2 = p.esrc[i0+2]; t2 = p.edst[i0+2];
        s3 = p.esrc[i0+3]; t3 = p.edst[i0+3];
        const int2* A0 = (const int2*)(p.vnf + (size_t)s0 * (DF/4));
        const int2* B0 = (const int2*)(p.vnf + (size_t)t0 * (DF/4));
        const int2* A1 = (const int2*)(p.vnf + (size_t)s1 * (DF/4));
        const int2* B1 = (const int2*)(p.vnf + (size_t)t1 * (DF/4));
        const int2* A2 = (const int2*)(p.vnf + (size_t)s2 * (DF/4));
        const int2* B2 = (const int2*)(p.vnf + (size_t)t2 * (DF/4));
        const int2* A3 = (const int2*)(p.vnf + (size_t)s3 * (DF/4));
        const int2* B3 = (const int2*)(p.vnf + (size_t)t3 * (DF/4));
        int2 a0 = A0[lane], b0 = B0[lane];
        int2 a1 = A1[lane], b1 = B1[lane];
        int2 a2 = A2[lane], b2 = B2[lane];
        int2 a3 = A3[lane], b3 = B3[lane];
        d0 = fp8dot4((unsigned)a0.x,(unsigned)b0.x) + fp8dot4((unsigned)a0.y,(unsigned)b0.y);
        d1 = fp8dot4((unsigned)a1.x,(unsigned)b1.x) + fp8dot4((unsigned)a1.y,(unsigned)b1.y);
        d2 = fp8dot4((unsigned)a2.x,(unsigned)b2.x) + fp8dot4((unsigned)a2.y,(unsigned)b2.y);
        d3 = fp8dot4((unsigned)a3.x,(unsigned)b3.x) + fp8dot4((unsigned)a3.y,(unsigned)b3.y);
    }
    #pragma unroll
    for (int off = 1; off < 64; off <<= 1) {
        d0 += __shfl_xor(d0, off);
        d1 += __shfl_xor(d1, off);
        d2 += __shfl_xor(d2, off);
        d3 += __shfl_xor(d3, off);
    }
    if (lane == 0) {
        d0 *= invp[s0] * invp[t0];
        d1 *= invp[s1] * invp[t1];
        d2 *= invp[s2] * invp[t2];
        d3 *= invp[s3] * invp[t3];
        ((float4*)p.w)[i0 >> 2] = make_float4(d0, d1, d2, d3);
    }
}

// ===== L5: CSR gather + projections + final =====
__global__ __launch_bounds__(256) void gather_kernel(Params p) {
    const int wave = threadIdx.x >> 6, lane = threadIdx.x & 63;
    const int node = blockIdx.x * 4 + wave;
    const bool bodyhalf = lane < 32;
    const int c = lane & 31;
    const int sbase = bodyhalf ? 0 : (NN + 1);
    const int eofs = bodyhalf ? 0 : NE;
    const float* hl = bodyhalf ? p.hlb : p.hlf;
    const int s0 = p.starts[sbase + node], s1 = p.starts[sbase + node + 1];
    float acc = 0.f;
    for (int i = s0; i < s1; i++) {
        float wv = p.w[eofs + i];
        int s = p.esrc[eofs + i];
        acc += wv * hl[(size_t)s * HC + c];
    }
    float pr = acc * (bodyhalf ? p.pb_W : p.pf_W)[c];
    #pragma unroll
    for (int off = 16; off > 0; off >>= 1) pr += __shfl_down(pr, off);
    float tot = __shfl(pr, 0) + __shfl(pr, 32);
    if (lane == 0) p.out[node] = p.ns[node] + tot + p.pb_b[0] + p.pf_b[0];
}

extern "C" void kernel_launch(void* const* d_in, const int* in_sizes, int n_in,
                              void* d_out, int out_size, void* d_ws, size_t ws_size,
                              hipStream_t stream) {
    char* ws = (char*)d_ws;
    size_t off = 0;
    auto alloc = [&](size_t bytes) { void* pp = ws + off; off += (bytes + 15) & ~size_t(15); return pp; };

    Params p;
    p.vb      = (const float*)d_in[1];
    p.vf      = (const float*)d_in[2];
    p.x       = (const float*)d_in[0];
    p.Wq      = (const float*)d_in[3];
    p.Wk      = (const float*)d_in[4];
    p.Wv      = (const float*)d_in[5];
    p.ln_g    = (const float*)d_in[6];
    p.ln_b    = (const float*)d_in[7];
    p.prelu_a = (const float*)d_in[8];
    p.mlp_W   = (const float*)d_in[9];
    p.mlp_b   = (const float*)d_in[10];
    p.np_W    = (const float*)d_in[11];
    p.np_b    = (const float*)d_in[12];
    p.body_W  = (const float*)d_in[13];
    p.body_b  = (const float*)d_in[14];
    p.face_W  = (const float*)d_in[15];
    p.face_b  = (const float*)d_in[16];
    p.pb_W    = (const float*)d_in[17];
    p.pb_b    = (const float*)d_in[18];
    p.pf_W    = (const float*)d_in[19];
    p.pf_b    = (const float*)d_in[20];
    p.eib     = (const int*)d_in[21];
    p.eif     = (const int*)d_in[22];
    p.vnb     = (unsigned*)alloc((size_t)NN*(DB/4)*4);   // 16 MB fp8
    p.vnf     = (unsigned*)alloc((size_t)NN*(DF/4)*4);   //  4 MB fp8
    p.invb    = (float*)alloc((size_t)NN*4);
    p.invf    = (float*)alloc((size_t)NN*4);
    p.a_ws    = (float*)alloc((size_t)NN*2*4);
    p.ns      = (float*)alloc((size_t)NN*4);
    p.hlb     = (float*)alloc((size_t)NN*HC*4);
    p.hlf     = (float*)alloc((size_t)NN*HC*4);
    p.w       = (float*)alloc((size_t)2*NE*4);
    p.counts  = (int*)alloc((size_t)2*NN*4);
    p.starts  = (int*)alloc((size_t)2*(NN+1)*4);
    p.cursor  = (int*)alloc((size_t)2*NN*4);
    p.esrc    = (int*)alloc((size_t)2*NE*4);
    p.edst    = (int*)alloc((size_t)2*NE*4);
    p.out     = (float*)d_out;

    hipMemsetAsync(p.counts, 0, (size_t)2*NN*4, stream);
    fused1_kernel<<<NN/4 + NN/4 + (2*NE)/256 + NB, 256, 0, stream>>>(p);
    fused2_kernel<<<2 + NN/4, 256, 0, stream>>>(p);
    fill_kernel<<<(2*NE)/256, 256, 0, stream>>>(p);
    wdot_kernel<<<2*(NE/16), 256, 0, stream>>>(p);
    gather_kernel<<<NN/4, 256, 0, stream>>>(p);
}

// Round 9
// 244.702 us; speedup vs baseline: 2.4804x; 1.0111x over previous
//
#include <hip/hip_runtime.h>

#define NN 8192     // nodes
#define NB 32       // graphs
#define NG 256      // nodes per graph
#define NE 65536    // edges per graph type
#define DK 512
#define HC 32
#define DB 2048     // body visual dim
#define DF 512      // face visual dim

#define BODY_DW (NN*DB/4)            // 4194304 dwords of fp8x4 (body)
#define FACE_DW (NN*DF/4)            // 1048576 dwords of fp8x4 (face)
#define P_BLOCKS 5120                // pack blocks: (BODY_DW+FACE_DW)/(256*4)

typedef float v2f __attribute__((ext_vector_type(2)));

#if __has_builtin(__builtin_amdgcn_cvt_pk_f32_fp8) && __has_builtin(__builtin_amdgcn_cvt_pk_fp8_f32)
#define HW_FP8 1
#else
#define HW_FP8 0
#endif

// ---- fp8 e4m3fn helpers (manual fallback only if builtins missing) ----
__device__ __forceinline__ float fp8_dec(unsigned u) {
    unsigned e = (u >> 3) & 15u, m = u & 7u, s = u & 0x80u;
    float v = e ? __uint_as_float(((e + 120u) << 23) | (m << 20))
                : (float)m * 0.001953125f;
    return s ? -v : v;
}
__device__ __forceinline__ unsigned fp8_enc(float x) {
    unsigned sb = (__float_as_uint(x) >> 24) & 0x80u;
    float a = fabsf(x);
    if (a >= 448.f) return sb | 0x7Eu;
    if (a < 0.015625f) {
        int c = (int)rintf(a * 512.f);
        if (c > 7) return sb | 0x08u;
        return sb | (unsigned)c;
    }
    int ex; (void)frexpf(a, &ex);
    float p = ldexpf(a, 1 - ex);
    int m = (int)rintf((p - 1.f) * 8.f);
    int e = ex - 1 + 7;
    if (m == 8) { m = 0; e++; }
    if (e >= 16) return sb | 0x7Eu;
    return sb | (unsigned)(e << 3) | (unsigned)m;
}
__device__ __forceinline__ unsigned pack4_fp8(float x, float y, float z, float w) {
#if HW_FP8
    int u = __builtin_amdgcn_cvt_pk_fp8_f32(x, y, 0, false);
    u = __builtin_amdgcn_cvt_pk_fp8_f32(z, w, u, true);
    return (unsigned)u;
#else
    return fp8_enc(x) | (fp8_enc(y) << 8) | (fp8_enc(z) << 16) | (fp8_enc(w) << 24);
#endif
}
__device__ __forceinline__ float fp8dot4(unsigned a, unsigned b) {
#if HW_FP8
    v2f al = __builtin_amdgcn_cvt_pk_f32_fp8((int)a, false);
    v2f ah = __builtin_amdgcn_cvt_pk_f32_fp8((int)a, true);
    v2f bl = __builtin_amdgcn_cvt_pk_f32_fp8((int)b, false);
    v2f bh = __builtin_amdgcn_cvt_pk_f32_fp8((int)b, true);
    return al.x*bl.x + al.y*bl.y + ah.x*bh.x + ah.y*bh.y;
#else
    float s = 0.f;
    #pragma unroll
    for (int j = 0; j < 4; j++)
        s += fp8_dec((a >> (8*j)) & 255u) * fp8_dec((b >> (8*j)) & 255u);
    return s;
#endif
}
__device__ __forceinline__ float fp8dot16(int4 a, int4 b) {
    return fp8dot4((unsigned)a.x, (unsigned)b.x) + fp8dot4((unsigned)a.y, (unsigned)b.y)
         + fp8dot4((unsigned)a.z, (unsigned)b.z) + fp8dot4((unsigned)a.w, (unsigned)b.w);
}

struct Params {
    const float *vb, *vf, *x, *Wq, *Wk, *Wv, *ln_g, *ln_b, *prelu_a;
    const float *mlp_W, *mlp_b, *np_W, *np_b, *body_W, *body_b, *face_W, *face_b;
    const float *pb_W, *pb_b, *pf_W, *pf_b;
    const int *eib, *eif;
    unsigned *vnb, *vnf;
    float *invb, *invf;
    float *a_ws, *ns, *hlb, *hlf, *w;
    int *counts, *starts, *cursor, *esrc, *edst;
    float *out;
};

// ===== K1: pure grid-stride fp8 pack + degree count + attention =====
// blocks [0, P_BLOCKS)              : elementwise fp8 pack (4 indep iters/thread)
// blocks [P_BLOCKS, +512)           : degree count
// blocks [P_BLOCKS+512, +NB)        : rank-2 attention
__global__ __launch_bounds__(256) void k1_kernel(Params p) {
    __shared__ float2 xs[NG];
    __shared__ float pm[4][4];
    __shared__ float sm4[4];
    const int bid = blockIdx.x, tid = threadIdx.x;
    const int lane = tid & 63, wave = tid >> 6;

    if (bid < P_BLOCKS) {
        const float4* vb4 = (const float4*)p.vb;
        const float4* vf4 = (const float4*)p.vf;
        const int stride = P_BLOCKS * 256;
        #pragma unroll
        for (int j = 0; j < 4; j++) {
            const int idx = j * stride + bid * 256 + tid;
            if (idx < BODY_DW) {
                float4 v = vb4[idx];
                p.vnb[idx] = pack4_fp8(v.x, v.y, v.z, v.w);
            } else {
                const int f = idx - BODY_DW;   // < FACE_DW by construction
                float4 v = vf4[f];
                p.vnf[f] = pack4_fp8(v.x, v.y, v.z, v.w);
            }
        }
    } else if (bid < P_BLOCKS + 512) {
        const int e = (bid - P_BLOCKS) * 256 + tid;
        if (e < NE) atomicAdd(&p.counts[p.eib[NE + e]], 1);
        else        atomicAdd(&p.counts[NN + p.eif[NE + (e - NE)]], 1);
    } else {
        const int gg = bid - (P_BLOCKS + 512);
        xs[tid] = ((const float2*)p.x)[gg*NG + tid];
        const int d = tid * 2;
        float q0a = p.Wq[d],    q0b = p.Wq[d+1];
        float q1a = p.Wq[DK+d], q1b = p.Wq[DK+d+1];
        float k0a = p.Wk[d],    k0b = p.Wk[d+1];
        float k1a = p.Wk[DK+d], k1b = p.Wk[DK+d+1];
        float m00 = q0a*k0a + q0b*k0b;
        float m01 = q0a*k1a + q0b*k1b;
        float m10 = q1a*k0a + q1b*k0b;
        float m11 = q1a*k1a + q1b*k1b;
        #pragma unroll
        for (int off = 32; off > 0; off >>= 1) {
            m00 += __shfl_down(m00,off); m01 += __shfl_down(m01,off);
            m10 += __shfl_down(m10,off); m11 += __shfl_down(m11,off);
        }
        if (lane == 0) { pm[wave][0]=m00; pm[wave][1]=m01; pm[wave][2]=m10; pm[wave][3]=m11; }
        __syncthreads();
        if (tid < 4) sm4[tid] = pm[0][tid] + pm[1][tid] + pm[2][tid] + pm[3][tid];
        __syncthreads();
        const float scale = 0.04419417382415922f;  // 1/sqrt(512)
        const float2 xi = xs[tid];
        const float u0 = (xi.x*sm4[0] + xi.y*sm4[2]) * scale;
        const float u1 = (xi.x*sm4[1] + xi.y*sm4[3]) * scale;
        float m = -1e30f;
        for (int j = 0; j < NG; j++) m = fmaxf(m, u0*xs[j].x + u1*xs[j].y);
        float S = 0.f, a0 = 0.f, a1 = 0.f;
        for (int j = 0; j < NG; j++) {
            float2 xj = xs[j];
            float pr = __expf(u0*xj.x + u1*xj.y - m);
            S += pr; a0 += pr*xj.x; a1 += pr*xj.y;
        }
        const float invS = 1.f / S;
        ((float2*)p.a_ws)[gg*NG + tid] = make_float2(a0*invS, a1*invS);
    }
}

// ===== K2: CSR scan + node MLP pipeline + invnorm from fp8 tables =====
// blocks 0,1                         : exclusive scan
// blocks [2, 2+NN/4)                 : node pipeline (1 node / wave)
// blocks [2+NN/4, 2+NN/2)            : body invnorm (1 row / wave, 8 dw/lane)
// blocks [2+NN/2, 2+3NN/4)           : face invnorm (1 row / wave, 2 dw/lane)
__global__ __launch_bounds__(256) void k2_kernel(Params p) {
    __shared__ int part[256];
    __shared__ float t[4][DK];
    __shared__ float hbuf[4][HC];
    const int bid = blockIdx.x, tid = threadIdx.x;
    const int wave = tid >> 6, lane = tid & 63;
    const int B_NODE = NN/4;

    if (bid < 2) {
        const int cbase = bid * NN;
        const int sbase = bid * (NN + 1);
        int loc[32];
        int sum = 0;
        #pragma unroll
        for (int j = 0; j < 32; j++) { loc[j] = p.counts[cbase + tid*32 + j]; sum += loc[j]; }
        part[tid] = sum;
        __syncthreads();
        for (int off = 1; off < 256; off <<= 1) {
            int v = (tid >= off) ? part[tid - off] : 0;
            __syncthreads();
            part[tid] += v;
            __syncthreads();
        }
        int run = (tid == 0) ? 0 : part[tid - 1];
        #pragma unroll
        for (int j = 0; j < 32; j++) {
            p.starts[sbase + tid*32 + j] = run;
            p.cursor[cbase + tid*32 + j] = run;
            run += loc[j];
        }
        if (tid == 255) p.starts[sbase + NN] = run;
        return;
    }
    if (bid < 2 + B_NODE) {
        const int node = (bid - 2) * 4 + wave;
        const float a0 = p.a_ws[node*2], a1 = p.a_ws[node*2+1];
        const float4* wv0 = (const float4*)p.Wv;
        const float4* wv1 = (const float4*)(p.Wv + DK);
        const float4* g4 = (const float4*)p.ln_g;
        const float4* b4 = (const float4*)p.ln_b;
        float4 W0[2], W1[2], Gg[2], Bb[2];
        #pragma unroll
        for (int k = 0; k < 2; k++) {
            int c4 = lane*2 + k;
            W0[k] = wv0[c4]; W1[k] = wv1[c4]; Gg[k] = g4[c4]; Bb[k] = b4[c4];
        }
        float s0=0.f, s1=0.f, q00=0.f, q01=0.f, q11=0.f;
        #pragma unroll
        for (int k = 0; k < 2; k++) {
            const float* u = (const float*)&W0[k];
            const float* v = (const float*)&W1[k];
            #pragma unroll
            for (int j = 0; j < 4; j++) {
                s0 += u[j]; s1 += v[j];
                q00 += u[j]*u[j]; q01 += u[j]*v[j]; q11 += v[j]*v[j];
            }
        }
        #pragma unroll
        for (int off = 1; off < 64; off <<= 1) {
            s0 += __shfl_xor(s0,off); s1 += __shfl_xor(s1,off);
            q00 += __shfl_xor(q00,off); q01 += __shfl_xor(q01,off); q11 += __shfl_xor(q11,off);
        }
        const float mean = (a0*s0 + a1*s1) * (1.f/DK);
        const float msq  = (a0*a0*q00 + 2.f*a0*a1*q01 + a1*a1*q11) * (1.f/DK);
        const float inv  = rsqrtf(msq - mean*mean + 1e-5f);
        const float alpha = p.prelu_a[0];
        #pragma unroll
        for (int k = 0; k < 2; k++) {
            int c4 = lane*2 + k;
            const float* u = (const float*)&W0[k];
            const float* v = (const float*)&W1[k];
            const float* gf = (const float*)&Gg[k];
            const float* bf = (const float*)&Bb[k];
            #pragma unroll
            for (int j = 0; j < 4; j++) {
                float od = a0*u[j] + a1*v[j];
                float nd = (od - mean) * inv * gf[j] + bf[j];
                t[wave][c4*4 + j] = (nd >= 0.f) ? nd : alpha*nd;
            }
        }
        __syncthreads();
        const int c = lane & 31, half = lane >> 5;
        const float* tp = t[wave] + half*256;
        const float* mw = p.mlp_W + half*256*HC + c;
        float partl = 0.f;
        for (int d = 0; d < 256; d++) partl += tp[d] * mw[d*HC];
        partl += __shfl_down(partl, 32);
        float hc = 0.f;
        if (lane < 32) { hc = partl + p.mlp_b[c]; hbuf[wave][c] = hc; }
        __syncthreads();
        float sp = (lane < 32) ? hc * p.np_W[c] : 0.f;
        #pragma unroll
        for (int off = 16; off > 0; off >>= 1) sp += __shfl_down(sp, off);
        if (lane == 0) p.ns[node] = sp + p.np_b[0];
        const float* hb_ = hbuf[wave];
        if (lane < 32) {
            float acc2 = p.body_b[c];
            #pragma unroll 8
            for (int cp = 0; cp < HC; cp++) acc2 += hb_[cp] * p.body_W[cp*HC + c];
            p.hlb[(size_t)node*HC + c] = acc2;
        } else {
            float acc2 = p.face_b[c];
            #pragma unroll 8
            for (int cp = 0; cp < HC; cp++) acc2 += hb_[cp] * p.face_W[cp*HC + c];
            p.hlf[(size_t)node*HC + c] = acc2;
        }
        return;
    }
    if (bid < 2 + B_NODE + NN/4) {
        const int node = (bid - 2 - B_NODE) * 4 + wave;
        const unsigned* row = p.vnb + (size_t)node * (DB/4);
        float ss = 0.f;
        #pragma unroll
        for (int k = 0; k < 8; k++) {
            unsigned u = row[lane + 64*k];
            ss += fp8dot4(u, u);
        }
        #pragma unroll
        for (int off = 1; off < 64; off <<= 1) ss += __shfl_xor(ss, off);
        if (lane == 0) p.invb[node] = rsqrtf(ss + 1e-8f);
        return;
    }
    {
        const int node = (bid - 2 - B_NODE - NN/4) * 4 + wave;
        const unsigned* row = p.vnf + (size_t)node * (DF/4);
        unsigned u0 = row[lane], u1 = row[lane + 64];
        float ss = fp8dot4(u0, u0) + fp8dot4(u1, u1);
        #pragma unroll
        for (int off = 1; off < 64; off <<= 1) ss += __shfl_xor(ss, off);
        if (lane == 0) p.invf[node] = rsqrtf(ss + 1e-8f);
    }
}

// ===== K3: CSR fill =====
__global__ __launch_bounds__(256) void fill_kernel(Params p) {
    const int e = blockIdx.x * 256 + threadIdx.x;
    if (e < NE) {
        int s = p.eib[e], d = p.eib[NE + e];
        int pos = atomicAdd(&p.cursor[d], 1);
        p.esrc[pos] = s; p.edst[pos] = d;
    } else {
        int e2 = e - NE;
        int s = p.eif[e2], d = p.eif[NE + e2];
        int pos = atomicAdd(&p.cursor[NN + d], 1);
        p.esrc[NE + pos] = s; p.edst[NE + pos] = d;
    }
}

// ===== K4: edge cosines in CSR order (4 edges / wave) =====
__global__ __launch_bounds__(256) void wdot_kernel(Params p) {
    const int wave = threadIdx.x >> 6, lane = threadIdx.x & 63;
    const int BB = NE/16;
    float d0, d1, d2, d3;
    int i0;
    int s0, s1, s2, s3, t0, t1, t2, t3;
    const float* invp;
    if (blockIdx.x < BB) {
        i0 = (blockIdx.x * 4 + wave) * 4;
        invp = p.invb;
        s0 = p.esrc[i0];   t0 = p.edst[i0];
        s1 = p.esrc[i0+1]; t1 = p.edst[i0+1];
        s2 = p.esrc[i0+2]; t2 = p.edst[i0+2];
        s3 = p.esrc[i0+3]; t3 = p.edst[i0+3];
        const int4* A0 = (const int4*)(p.vnb + (size_t)s0 * (DB/4));
        const int4* B0 = (const int4*)(p.vnb + (size_t)t0 * (DB/4));
        const int4* A1 = (const int4*)(p.vnb + (size_t)s1 * (DB/4));
        const int4* B1 = (const int4*)(p.vnb + (size_t)t1 * (DB/4));
        const int4* A2 = (const int4*)(p.vnb + (size_t)s2 * (DB/4));
        const int4* B2 = (const int4*)(p.vnb + (size_t)t2 * (DB/4));
        const int4* A3 = (const int4*)(p.vnb + (size_t)s3 * (DB/4));
        const int4* B3 = (const int4*)(p.vnb + (size_t)t3 * (DB/4));
        int4 a00 = A0[lane], a01 = A0[lane+64];
        int4 b00 = B0[lane], b01 = B0[lane+64];
        int4 a10 = A1[lane], a11 = A1[lane+64];
        int4 b10 = B1[lane], b11 = B1[lane+64];
        int4 a20 = A2[lane], a21 = A2[lane+64];
        int4 b20 = B2[lane], b21 = B2[lane+64];
        int4 a30 = A3[lane], a31 = A3[lane+64];
        int4 b30 = B3[lane], b31 = B3[lane+64];
        d0 = fp8dot16(a00,b00) + fp8dot16(a01,b01);
        d1 = fp8dot16(a10,b10) + fp8dot16(a11,b11);
        d2 = fp8dot16(a20,b20) + fp8dot16(a21,b21);
        d3 = fp8dot16(a30,b30) + fp8dot16(a31,b31);
    } else {
        i0 = NE + ((blockIdx.x - BB) * 4 + wave) * 4;
        invp = p.invf;
        s0 = p.esrc[i0];   t0 = p.edst[i0];
        s1 = p.esrc[i0+1]; t1 = p.edst[i0+1];
        s2 = p.esrc[i0+2]; t2 = p.edst[i0+2];
        s3 = p.esrc[i0+3]; t3 = p.edst[i0+3];
        const int2* A0 = (const int2*)(p.vnf + (size_t)s0 * (DF/4));
        const int2* B0 = (const int2*)(p.vnf + (size_t)t0 * (DF/4));
        const int2* A1 = (const int2*)(p.vnf + (size_t)s1 * (DF/4));
        const int2* B1 = (const int2*)(p.vnf + (size_t)t1 * (DF/4));
        const int2* A2 = (const int2*)(p.vnf + (size_t)s2 * (DF/4));
        const int2* B2 = (const int2*)(p.vnf + (size_t)t2 * (DF/4));
        const int2* A3 = (const int2*)(p.vnf + (size_t)s3 * (DF/4));
        const int2* B3 = (const int2*)(p.vnf + (size_t)t3 * (DF/4));
        int2 a0 = A0[lane], b0 = B0[lane];
        int2 a1 = A1[lane], b1 = B1[lane];
        int2 a2 = A2[lane], b2 = B2[lane];
        int2 a3 = A3[lane], b3 = B3[lane];
        d0 = fp8dot4((unsigned)a0.x,(unsigned)b0.x) + fp8dot4((unsigned)a0.y,(unsigned)b0.y);
        d1 = fp8dot4((unsigned)a1.x,(unsigned)b1.x) + fp8dot4((unsigned)a1.y,(unsigned)b1.y);
        d2 = fp8dot4((unsigned)a2.x,(unsigned)b2.x) + fp8dot4((unsigned)a2.y,(unsigned)b2.y);
        d3 = fp8dot4((unsigned)a3.x,(unsigned)b3.x) + fp8dot4((unsigned)a3.y,(unsigned)b3.y);
    }
    #pragma unroll
    for (int off = 1; off < 64; off <<= 1) {
        d0 += __shfl_xor(d0, off);
        d1 += __shfl_xor(d1, off);
        d2 += __shfl_xor(d2, off);
        d3 += __shfl_xor(d3, off);
    }
    if (lane == 0) {
        d0 *= invp[s0] * invp[t0];
        d1 *= invp[s1] * invp[t1];
        d2 *= invp[s2] * invp[t2];
        d3 *= invp[s3] * invp[t3];
        ((float4*)p.w)[i0 >> 2] = make_float4(d0, d1, d2, d3);
    }
}

// ===== K5: CSR gather + projections + final =====
__global__ __launch_bounds__(256) void gather_kernel(Params p) {
    const int wave = threadIdx.x >> 6, lane = threadIdx.x & 63;
    const int node = blockIdx.x * 4 + wave;
    const bool bodyhalf = lane < 32;
    const int c = lane & 31;
    const int sbase = bodyhalf ? 0 : (NN + 1);
    const int eofs = bodyhalf ? 0 : NE;
    const float* hl = bodyhalf ? p.hlb : p.hlf;
    const int s0 = p.starts[sbase + node], s1 = p.starts[sbase + node + 1];
    float acc = 0.f;
    for (int i = s0; i < s1; i++) {
        float wv = p.w[eofs + i];
        int s = p.esrc[eofs + i];
        acc += wv * hl[(size_t)s * HC + c];
    }
    float pr = acc * (bodyhalf ? p.pb_W : p.pf_W)[c];
    #pragma unroll
    for (int off = 16; off > 0; off >>= 1) pr += __shfl_down(pr, off);
    float tot = __shfl(pr, 0) + __shfl(pr, 32);
    if (lane == 0) p.out[node] = p.ns[node] + tot + p.pb_b[0] + p.pf_b[0];
}

extern "C" void kernel_launch(void* const* d_in, const int* in_sizes, int n_in,
                              void* d_out, int out_size, void* d_ws, size_t ws_size,
                              hipStream_t stream) {
    char* ws = (char*)d_ws;
    size_t off = 0;
    auto alloc = [&](size_t bytes) { void* pp = ws + off; off += (bytes + 15) & ~size_t(15); return pp; };

    Params p;
    p.vb      = (const float*)d_in[1];
    p.vf      = (const float*)d_in[2];
    p.x       = (const float*)d_in[0];
    p.Wq      = (const float*)d_in[3];
    p.Wk      = (const float*)d_in[4];
    p.Wv      = (const float*)d_in[5];
    p.ln_g    = (const float*)d_in[6];
    p.ln_b    = (const float*)d_in[7];
    p.prelu_a = (const float*)d_in[8];
    p.mlp_W   = (const float*)d_in[9];
    p.mlp_b   = (const float*)d_in[10];
    p.np_W    = (const float*)d_in[11];
    p.np_b    = (const float*)d_in[12];
    p.body_W  = (const float*)d_in[13];
    p.body_b  = (const float*)d_in[14];
    p.face_W  = (const float*)d_in[15];
    p.face_b  = (const float*)d_in[16];
    p.pb_W    = (const float*)d_in[17];
    p.pb_b    = (const float*)d_in[18];
    p.pf_W    = (const float*)d_in[19];
    p.pf_b    = (const float*)d_in[20];
    p.eib     = (const int*)d_in[21];
    p.eif     = (const int*)d_in[22];
    p.vnb     = (unsigned*)alloc((size_t)BODY_DW*4);     // 16 MB fp8
    p.vnf     = (unsigned*)alloc((size_t)FACE_DW*4);     //  4 MB fp8
    p.invb    = (float*)alloc((size_t)NN*4);
    p.invf    = (float*)alloc((size_t)NN*4);
    p.a_ws    = (float*)alloc((size_t)NN*2*4);
    p.ns      = (float*)alloc((size_t)NN*4);
    p.hlb     = (float*)alloc((size_t)NN*HC*4);
    p.hlf     = (float*)alloc((size_t)NN*HC*4);
    p.w       = (float*)alloc((size_t)2*NE*4);
    p.counts  = (int*)alloc((size_t)2*NN*4);
    p.starts  = (int*)alloc((size_t)2*(NN+1)*4);
    p.cursor  = (int*)alloc((size_t)2*NN*4);
    p.esrc    = (int*)alloc((size_t)2*NE*4);
    p.edst    = (int*)alloc((size_t)2*NE*4);
    p.out     = (float*)d_out;

    hipMemsetAsync(p.counts, 0, (size_t)2*NN*4, stream);
    k1_kernel<<<P_BLOCKS + 512 + NB, 256, 0, stream>>>(p);
    k2_kernel<<<2 + NN/4 + NN/4 + NN/4, 256, 0, stream>>>(p);
    fill_kernel<<<(2*NE)/256, 256, 0, stream>>>(p);
    wdot_kernel<<<2*(NE/16), 256, 0, stream>>>(p);
    gather_kernel<<<NN/4, 256, 0, stream>>>(p);
}